// Round 10
// baseline (138.671 us; speedup 1.0000x reference)
//
#include <hip/hip_runtime.h>

#define WTH 64
#define NTH 256
#define NBOX 16384
#define NCLSIN 91
#define NCLS 90
#define MAXSEL 100
#define TOPK 200
#define CAP 1024      // global candidate list stride per (b,c)
#define CANDL 512     // band capacity (C ~ 246 +- 16; >512 = 17 sigma)
#define CBCAP 384     // staged boxes/areas
#define WK 160        // suppression-matrix width (first WK sorted candidates)
#define BINS 1024     // topk radix bins
#define GRP 4         // BINS / NTH
#define T0 0.985f     // band threshold; exact fallbacks guard
#define BOXPB 256     // boxes per filter block
#define KSL 16        // per-class LDS slots per filter block
#define OVFC 64       // LDS overflow list capacity
#define CNTSTR 16     // cnt_g stride in ints (64B per counter)

// order-preserving fp32 <-> u32 (strictly monotone for all non-NaN)
__device__ __forceinline__ unsigned fmap(float f) {
    unsigned u = __float_as_uint(f);
    return (u & 0x80000000u) ? ~u : (u | 0x80000000u);
}
__device__ __forceinline__ float funmap(unsigned u) {
    unsigned b = (u & 0x80000000u) ? (u ^ 0x80000000u) : ~u;
    return __uint_as_float(b);
}
__device__ __forceinline__ unsigned long long shfl_xor_u64(unsigned long long v, int mask) {
    unsigned lo = (unsigned)(v & 0xFFFFFFFFull);
    unsigned hi = (unsigned)(v >> 32);
    lo = __shfl_xor(lo, mask, 64);
    hi = __shfl_xor(hi, mask, 64);
    return ((unsigned long long)hi << 32) | (unsigned long long)lo;
}

// exact reference IoU>0.5 test (same op order, real IEEE div, no FMA).
// IoU is symmetric, and __fadd_rn is commutative -> operand order safe.
__device__ __forceinline__ bool sup_test(float4 s, float sa, float4 c, float ca) {
    float y1 = fmaxf(s.x, c.x);
    float x1 = fmaxf(s.y, c.y);
    float y2 = fminf(s.z, c.z);
    float x2 = fminf(s.w, c.w);
    float dy = fmaxf(__fsub_rn(y2, y1), 0.f);
    float dx = fmaxf(__fsub_rn(x2, x1), 0.f);
    float inter = __fmul_rn(dy, dx);
    float uni = __fsub_rn(__fadd_rn(sa, ca), inter);
    return (uni > 0.f) && (__fdiv_rn(inter, uni) > 0.5f);
}
__device__ __forceinline__ float box_area(float4 b) {
    return __fmul_rn(__fsub_rn(b.z, b.x), __fsub_rn(b.w, b.y));
}

// ---------------------------------------------------------------------------
__global__ __launch_bounds__(NTH) void zero_k(int4* __restrict__ p, int n4) {
    int i = blockIdx.x * NTH + threadIdx.x;
    if (i < n4) p[i] = make_int4(0, 0, 0, 0);
}

// ---------------------------------------------------------------------------
__device__ __forceinline__ void emit_hit(unsigned long long pk, int b, int n0,
                                         int* cnt_s, unsigned long long* ent,
                                         unsigned* ovf_meta,
                                         unsigned long long* ovf_key,
                                         int* sh_ovf, int* cnt_g) {
    unsigned ee = (unsigned)pk;
    int row = (int)ee / NCLSIN;
    int c = (int)ee - row * NCLSIN;
    if (c == 0) return;  // background
    unsigned i = (unsigned)(n0 + row);
    unsigned long long key = (pk & 0xFFFFFFFF00000000ull) | (0xFFFFFFFFu - i);
    int r = atomicAdd(&cnt_s[c], 1);
    if (r < KSL) {
        ent[c * KSL + r] = key;
    } else {
        int o = atomicAdd(sh_ovf, 1);
        if (o < OVFC) {
            ovf_meta[o] = ((unsigned)c << 16) | (unsigned)r;
            ovf_key[o] = key;
        } else {
            atomicAdd(&cnt_g[(b * NCLS + c - 1) * CNTSTR], CAP + 1);
        }
    }
}

// ---------------------------------------------------------------------------
// Kernel 0: stream scores once; hits -> per-class lists (see r6 notes).
// ---------------------------------------------------------------------------
__global__ __launch_bounds__(NTH) void filter_k(const float* __restrict__ in,
                                                unsigned long long* __restrict__ cand_g,
                                                int* __restrict__ cnt_g) {
    __shared__ int cnt_s[NCLSIN];
    __shared__ int base_s[NCLSIN];
    __shared__ unsigned long long ent[NCLSIN * KSL];
    __shared__ unsigned ovf_meta[OVFC];
    __shared__ unsigned long long ovf_key[OVFC];
    __shared__ int sh_ovf;

    const int tid = threadIdx.x;
    const int n0 = blockIdx.x * BOXPB;
    const int b = blockIdx.y;
    const int NF4 = BOXPB * NCLSIN / 4;

    for (int i = tid; i < NCLSIN; i += NTH) cnt_s[i] = 0;
    if (tid == 0) sh_ovf = 0;
    __syncthreads();

    unsigned long long q0 = 0, q1 = 0, q2 = 0, q3 = 0;
    int lc = 0;

    const float4* src = (const float4*)(in + ((size_t)b * NBOX + n0) * NCLSIN);
    for (int i = tid; i < NF4; i += 2 * NTH) {
        float4 v1 = src[i];
        int i2 = i + NTH;
        bool has2 = i2 < NF4;
        float4 v2 = make_float4(0.f, 0.f, 0.f, 0.f);
        if (has2) v2 = src[i2];
        float mx1 = fmaxf(fmaxf(v1.x, v1.y), fmaxf(v1.z, v1.w));
        float mx2 = fmaxf(fmaxf(v2.x, v2.y), fmaxf(v2.z, v2.w));
        if (fmaxf(mx1, mx2) > T0) {
#pragma unroll
            for (int h = 0; h < 2; ++h) {
                float4 v = h ? v2 : v1;
                float mx = h ? mx2 : mx1;
                int eb = (h ? i2 : i) * 4;
                if (mx > T0) {
                    const float sv[4] = {v.x, v.y, v.z, v.w};
#pragma unroll
                    for (int qq = 0; qq < 4; ++qq) {
                        float s = sv[qq];
                        if (s > T0) {
                            unsigned long long pk =
                                ((unsigned long long)fmap(s) << 32) |
                                (unsigned)(eb + qq);
                            if (lc == 0) q0 = pk;
                            else if (lc == 1) q1 = pk;
                            else if (lc == 2) q2 = pk;
                            else if (lc == 3) q3 = pk;
                            else emit_hit(pk, b, n0, cnt_s, ent, ovf_meta,
                                          ovf_key, &sh_ovf, cnt_g);
                            ++lc;
                        }
                    }
                }
            }
        }
    }
    if (lc > 0) emit_hit(q0, b, n0, cnt_s, ent, ovf_meta, ovf_key, &sh_ovf, cnt_g);
    if (lc > 1) emit_hit(q1, b, n0, cnt_s, ent, ovf_meta, ovf_key, &sh_ovf, cnt_g);
    if (lc > 2) emit_hit(q2, b, n0, cnt_s, ent, ovf_meta, ovf_key, &sh_ovf, cnt_g);
    if (lc > 3) emit_hit(q3, b, n0, cnt_s, ent, ovf_meta, ovf_key, &sh_ovf, cnt_g);
    __syncthreads();

    if (tid >= 1 && tid < NCLSIN) {
        int c = tid;
        int n = cnt_s[c];
        int base = 0;
        if (n > 0) {
            int bc = b * NCLS + c - 1;
            base = atomicAdd(&cnt_g[bc * CNTSTR], n);
            int lim = n < KSL ? n : KSL;
            for (int j = 0; j < lim; ++j) {
                int pos = base + j;
                if (pos < CAP) cand_g[(size_t)bc * CAP + pos] = ent[c * KSL + j];
            }
        }
        base_s[c] = base;
    }
    __syncthreads();

    int no = sh_ovf < OVFC ? sh_ovf : OVFC;
    for (int o = tid; o < no; o += NTH) {
        unsigned m = ovf_meta[o];
        int c = (int)(m >> 16);
        int r = (int)(m & 0xFFFFu);
        int bc = b * NCLS + c - 1;
        int pos = base_s[c] + r;
        if (pos < CAP) cand_g[(size_t)bc * CAP + pos] = ovf_key[o];
    }
}

// 256-thread bitonic sort descending, zero-padded to pow2
__device__ __forceinline__ void sort_desc(unsigned long long* cand, int M, int tid) {
    int P = 1;
    while (P < M) P <<= 1;
    for (int i = M + tid; i < P; i += NTH) cand[i] = 0ull;
    __syncthreads();
    for (int kk = 2; kk <= P; kk <<= 1) {
        for (int jj = kk >> 1; jj > 0; jj >>= 1) {
            for (int i = tid; i < P; i += NTH) {
                int ixj = i ^ jj;
                if (ixj > i) {
                    unsigned long long a = cand[i], c = cand[ixj];
                    bool sw = ((i & kk) == 0) ? (a < c) : (a > c);
                    if (sw) { cand[i] = c; cand[ixj] = a; }
                }
            }
            __syncthreads();
        }
    }
}

// ---------------------------------------------------------------------------
// Kernel 1: one 256-thr block per (batch, class).
// load band -> sort -> gather -> wave-parallel WKxWK forward-suppression
// bit matrix (row per wave, ballot-packed) -> single-lane bit walk ->
// exact serial-walk tail [WK, C) -> exact argmax fallback below band.
// ---------------------------------------------------------------------------
__global__ __launch_bounds__(NTH) void nms_k(
    const unsigned long long* __restrict__ cand_g,
    const int* __restrict__ cnt_g,
    const float* __restrict__ scores_raw,
    const float4* __restrict__ boxes,
    float* __restrict__ ws_sc, float* __restrict__ ws_bx, int use_band) {
    __shared__ unsigned long long cand[CANDL];     // 4 KB
    __shared__ float4 candbox[CBCAP];              // 6 KB
    __shared__ float carea[CBCAP];                 // 1.5 KB
    __shared__ unsigned long long colmask[WK * 3]; // 3.75 KB
    __shared__ float4 selbox[MAXSEL];              // 1.6 KB
    __shared__ float selscore[MAXSEL];
    __shared__ float selarea[MAXSEL];
    __shared__ int sellist[MAXSEL];
    __shared__ int sh_nsel;

    const int tid = threadIdx.x;
    const int wv = tid >> 6, ln = tid & 63;
    const int bc = blockIdx.x;
    const int b = bc / NCLS;
    const int c0 = bc - b * NCLS;
    const float* sraw = scores_raw + (size_t)b * NBOX * NCLSIN + (c0 + 1);
    const float4* bbase = boxes + (size_t)b * NBOX;

    int nsel = 0;
    unsigned long long lastk = ~0ull;

    const int C = use_band ? cnt_g[bc * CNTSTR] : 0;
    if (use_band && C > 0 && C <= CANDL) {
        for (int i = tid; i < C; i += NTH)
            cand[i] = cand_g[(size_t)bc * CAP + i];
        sort_desc(cand, C, tid);
        const int PBX = C < CBCAP ? C : CBCAP;
        for (int i = tid; i < PBX; i += NTH) {
            float4 bx = bbase[(int)(0xFFFFFFFFu - (unsigned)cand[i])];
            candbox[i] = bx;
            carea[i] = box_area(bx);
        }
        __syncthreads();
        const int W = C < WK ? C : WK;

        // ---- forward-suppression matrix, one row per wave, ballot-packed.
        // colmask[r] bit j (j<r): sorted-candidate j suppresses candidate r.
        for (int r = wv; r < W; r += 4) {
            float4 br = candbox[r];     // uniform per wave -> LDS broadcast
            float ar = carea[r];
            unsigned long long m0 = 0, m1 = 0, m2 = 0;
            {
                int j = ln;
                bool s = (j < r) && sup_test(candbox[j], carea[j], br, ar);
                m0 = __ballot(s);
            }
            if (r > 64) {
                int j = 64 + ln;
                bool s = (j < r) && sup_test(candbox[j], carea[j], br, ar);
                m1 = __ballot(s);
            }
            if (r > 128) {
                int j = 128 + ln;
                bool s = (j < r) && sup_test(candbox[j], carea[j], br, ar);
                m2 = __ballot(s);
            }
            if (ln == 0) {
                colmask[r * 3 + 0] = m0;
                colmask[r * 3 + 1] = m1;
                colmask[r * 3 + 2] = m2;
            }
        }
        __syncthreads();

        // ---- single-lane bit walk (selection state = 3 registers)
        if (tid == 0) {
            unsigned long long sb0 = 0, sb1 = 0, sb2 = 0;
            int ns = 0;
            for (int m = 0; m < W; ++m) {
                unsigned long long hit = (colmask[m * 3] & sb0) |
                                         (colmask[m * 3 + 1] & sb1) |
                                         (colmask[m * 3 + 2] & sb2);
                if (!hit) {
                    sellist[ns++] = m;
                    if (m < 64) sb0 |= 1ull << m;
                    else if (m < 128) sb1 |= 1ull << (m - 64);
                    else sb2 |= 1ull << (m - 128);
                    if (ns >= MAXSEL) break;
                }
            }
            sh_nsel = ns;
        }
        __syncthreads();
        nsel = sh_nsel;
        for (int k = tid; k < nsel; k += NTH) {
            int m = sellist[k];
            selscore[k] = funmap((unsigned)(cand[m] >> 32));
            selbox[k] = candbox[m];
            selarea[k] = carea[m];
        }
        __syncthreads();

        // ---- exact serial-walk tail over [W, C) (wave 0)
        if (nsel < MAXSEL && C > W) {
            if (tid < 64) {
                for (int m = W; m < C && nsel < MAXSEL; ++m) {
                    unsigned long long key = cand[m];
                    float4 bx = (m < CBCAP) ? candbox[m]
                                            : bbase[(int)(0xFFFFFFFFu - (unsigned)key)];
                    float ca = (m < CBCAP) ? carea[m] : box_area(bx);
                    bool sup = false;
                    if (tid < nsel) sup = sup_test(selbox[tid], selarea[tid], bx, ca);
                    int l2 = tid + 64;
                    if (l2 < nsel) sup = sup || sup_test(selbox[l2], selarea[l2], bx, ca);
                    if (!__any(sup)) {
                        if (tid == 0) {
                            selbox[nsel] = bx;
                            selarea[nsel] = ca;
                            selscore[nsel] = funmap((unsigned)(key >> 32));
                        }
                        nsel++;
                    }
                }
                if (tid == 0) sh_nsel = nsel;
            }
            __syncthreads();
            nsel = sh_nsel;
        }
        lastk = cand[C - 1];
    }

    // ---- exact argmax fallback + outputs: wave 0 only (no barriers inside)
    if (tid < 64) {
        while (nsel < MAXSEL) {
            unsigned long long best = 0ull;
            for (int i = tid; i < NBOX; i += WTH) {
                float s = sraw[(size_t)i * NCLSIN];
                if (s > 0.3f) {
                    unsigned long long key =
                        ((unsigned long long)fmap(s) << 32) | (0xFFFFFFFFu - (unsigned)i);
                    if (key < lastk && key > best) best = key;
                }
            }
#pragma unroll
            for (int off = 32; off > 0; off >>= 1) {
                unsigned long long o = shfl_xor_u64(best, off);
                best = best > o ? best : o;
            }
            if (best == 0ull) break;
            lastk = best;
            float4 bx = bbase[(int)(0xFFFFFFFFu - (unsigned)best)];
            float ca = box_area(bx);
            bool sup = false;
            if (tid < nsel) sup = sup_test(selbox[tid], selarea[tid], bx, ca);
            int l2 = tid + 64;
            if (l2 < nsel) sup = sup || sup_test(selbox[l2], selarea[l2], bx, ca);
            if (!__any(sup)) {
                if (tid == 0) {
                    selbox[nsel] = bx;
                    selarea[nsel] = ca;
                    selscore[nsel] = funmap((unsigned)(best >> 32));
                }
                nsel++;
            }
        }

        float* scp = ws_sc + (size_t)bc * MAXSEL;
        float4* bxp = (float4*)(ws_bx + (size_t)bc * MAXSEL * 4);
        {
            bool v = tid < nsel;
            scp[tid] = v ? selscore[tid] : 0.f;
            bxp[tid] = v ? selbox[tid] : make_float4(0.f, 0.f, 0.f, 0.f);
        }
        int j1 = tid + 64;
        if (j1 < MAXSEL) {
            bool v = j1 < nsel;
            scp[j1] = v ? selscore[j1] : 0.f;
            bxp[j1] = v ? selbox[j1] : make_float4(0.f, 0.f, 0.f, 0.f);
        }
    }
}

__device__ __forceinline__ void bin_select(unsigned* hist, unsigned* gbuf,
                                           int* sh_g, int* sh_b, unsigned* sh_pb,
                                           int tid, unsigned need) {
    unsigned gs = 0;
#pragma unroll
    for (int q = 0; q < GRP; ++q) gs += hist[tid * GRP + q];
    gbuf[tid] = gs;
    __syncthreads();
    for (int off = 1; off < NTH; off <<= 1) {
        unsigned add = (tid >= off) ? gbuf[tid - off] : 0u;
        __syncthreads();
        gbuf[tid] += add;
        __syncthreads();
    }
    if (tid == 0) *sh_g = NTH - 1;
    __syncthreads();
    if (gbuf[tid] >= need && (tid == 0 || gbuf[tid - 1] < need)) *sh_g = tid;
    __syncthreads();
    if (tid == 0) {
        int g = *sh_g;
        unsigned acc = (g > 0) ? gbuf[g - 1] : 0u;
        int bs = g * GRP + (GRP - 1);
        unsigned pb = acc;
#pragma unroll
        for (int q = 0; q < GRP; ++q) {
            acc += hist[g * GRP + q];
            if (acc >= need) { bs = g * GRP + q; pb = acc; break; }
            pb = acc;
        }
        *sh_b = bs; *sh_pb = pb;
    }
    __syncthreads();
}

// ---------------------------------------------------------------------------
// Kernel 2: one block per batch: stable top-200 of 9000 via radix-select+sort.
// ---------------------------------------------------------------------------
__global__ __launch_bounds__(NTH) void topk_k(const float* __restrict__ ws_sc,
                                              const float* __restrict__ ws_bx,
                                              float* __restrict__ out_sc,
                                              float* __restrict__ out_bx) {
    __shared__ unsigned hist[BINS];
    __shared__ unsigned gbuf[NTH];
    __shared__ unsigned long long cand[CAP];
    __shared__ unsigned sh_kmax, sh_pb;
    __shared__ int sh_E, sh_g, sh_b, sh_cnt;

    const int tid = threadIdx.x;
    const int b = blockIdx.x;
    const int NF = NCLS * MAXSEL;  // 9000
    const float* sp = ws_sc + (size_t)b * NF;

    unsigned km = 0, ce = 0;
    for (int f = tid; f < NF; f += NTH) {
        unsigned k = __float_as_uint(sp[f]);
        if (k) { ce++; km = km > k ? km : k; }
    }
#pragma unroll
    for (int off = 32; off > 0; off >>= 1) {
        unsigned o = (unsigned)__shfl_xor((int)km, off, 64);
        km = km > o ? km : o;
        ce += (unsigned)__shfl_xor((int)ce, off, 64);
    }
    if ((tid & 63) == 0) { gbuf[tid >> 6] = km; gbuf[8 + (tid >> 6)] = ce; }
    __syncthreads();
    if (tid == 0) {
        unsigned m2 = 0, c2 = 0;
        for (int w = 0; w < NTH / 64; ++w) {
            m2 = m2 > gbuf[w] ? m2 : gbuf[w];
            c2 += gbuf[8 + w];
        }
        sh_kmax = m2; sh_E = (int)c2;
    }
    __syncthreads();
    const int E = sh_E;
    const unsigned kmax = sh_kmax;

    unsigned thr = 1u;
    if (E > TOPK) {
        for (int shift = 8;; shift += 4) {
            for (int i = tid; i < BINS; i += NTH) hist[i] = 0u;
            __syncthreads();
            for (int f = tid; f < NF; f += NTH) {
                unsigned k = __float_as_uint(sp[f]);
                if (k) {
                    unsigned bin = (kmax - k) >> shift;
                    if (bin < BINS - 1) atomicAdd(&hist[bin], 1u);
                }
            }
            __syncthreads();
            bin_select(hist, gbuf, &sh_g, &sh_b, &sh_pb, tid, (unsigned)TOPK);
            if (sh_b < BINS - 1) {
                long long t = (long long)kmax - ((long long)(sh_b + 1) << shift) + 1;
                thr = (t < 1) ? 1u : (unsigned)t;
                break;
            }
        }
    }

    if (tid == 0) sh_cnt = 0;
    __syncthreads();
    for (int f = tid; f < NF; f += NTH) {
        unsigned k = __float_as_uint(sp[f]);
        if (k >= thr) {
            int pos = atomicAdd(&sh_cnt, 1);
            if (pos < CAP)
                cand[pos] = ((unsigned long long)k << 32) | (0xFFFFFFFFu - (unsigned)f);
        }
    }
    __syncthreads();
    int M = sh_cnt < CAP ? sh_cnt : CAP;

    if (M < TOPK) {
        int lim = M + TOPK;
        if (lim > NF) lim = NF;
        for (int f = tid; f < lim; f += NTH) {
            unsigned k = __float_as_uint(sp[f]);
            if (k == 0) {
                int pos = atomicAdd(&sh_cnt, 1);
                if (pos < CAP)
                    cand[pos] = (unsigned long long)(0xFFFFFFFFu - (unsigned)f);
            }
        }
        __syncthreads();
        M = sh_cnt < CAP ? sh_cnt : CAP;
    }

    sort_desc(cand, M, tid);

    for (int k = tid; k < TOPK; k += NTH) {
        float cls = 0.f, s = 0.f;
        float4 bx = make_float4(0.f, 0.f, 0.f, 0.f);
        if (k < M) {
            unsigned long long key = cand[k];
            unsigned f = 0xFFFFFFFFu - (unsigned)key;
            s = __uint_as_float((unsigned)(key >> 32));
            cls = (s > 0.f) ? (float)(f / MAXSEL + 1) : 0.f;
            bx = *(const float4*)(ws_bx + ((size_t)b * NF + f) * 4);
        }
        out_sc[((size_t)b * TOPK + k) * 2 + 0] = cls;
        out_sc[((size_t)b * TOPK + k) * 2 + 1] = s;
        ((float4*)out_bx)[(size_t)b * TOPK + k] = bx;
    }
}

// ---------------------------------------------------------------------------
extern "C" void kernel_launch(void* const* d_in, const int* in_sizes, int n_in,
                              void* d_out, int out_size, void* d_ws, size_t ws_size,
                              hipStream_t stream) {
    const float* scores = (const float*)d_in[0];
    const float4* boxes = (const float4*)d_in[1];
    float* out = (float*)d_out;

    const int B = in_sizes[1] / (NBOX * 4);
    const int NBC = B * NCLS;

    // ws layout: cnt [NBC * CNTSTR ints] | cand [NBC*CAP u64] | sc | bx
    size_t off_cand = ((size_t)NBC * CNTSTR * 4 + 15) & ~(size_t)15;
    size_t off_sc = off_cand + (size_t)NBC * CAP * 8;
    size_t off_bx = off_sc + (size_t)NBC * MAXSEL * 4;
    size_t need = off_bx + (size_t)NBC * MAXSEL * 16;

    char* ws = (char*)d_ws;
    bool use_band = ws_size >= need;

    int* cnt_g;
    unsigned long long* cand_g;
    float *ws_sc, *ws_bx;
    if (use_band) {
        cnt_g = (int*)ws;
        cand_g = (unsigned long long*)(ws + off_cand);
        ws_sc = (float*)(ws + off_sc);
        ws_bx = (float*)(ws + off_bx);
    } else {
        cnt_g = (int*)ws;                  // unused
        cand_g = (unsigned long long*)ws;  // unused
        ws_sc = (float*)ws;
        ws_bx = ws_sc + (size_t)NBC * MAXSEL;
    }

    if (use_band) {
        int n4 = NBC * CNTSTR / 4;
        zero_k<<<(n4 + NTH - 1) / NTH, NTH, 0, stream>>>((int4*)cnt_g, n4);
        filter_k<<<dim3(NBOX / BOXPB, B), NTH, 0, stream>>>(scores, cand_g, cnt_g);
    }
    nms_k<<<NBC, NTH, 0, stream>>>(cand_g, cnt_g, scores, boxes,
                                   ws_sc, ws_bx, use_band ? 1 : 0);
    topk_k<<<B, NTH, 0, stream>>>(ws_sc, ws_bx, out, out + (size_t)B * TOPK * 2);
}

// Round 11
// 131.170 us; speedup vs baseline: 1.0572x; 1.0572x over previous
//
#include <hip/hip_runtime.h>

#define NTH 256
#define NBOX 16384
#define NCLSIN 91
#define NCLS 90
#define MAXSEL 100
#define TOPK 200
#define TSEL 256      // fallback radix-select size
#define CAP 1024      // candidate list capacity per (b,c)
#define CBCAP 384     // prefetched candidate boxes (band C ~ 246 +- 16)
#define BINS 1024
#define GRP 4         // BINS / NTH
#define T0 0.985f     // band threshold: E[hits/class]=246; exact refill guards
#define BOXPB 256     // boxes per filter block
#define KSL 16        // per-class LDS slots per filter block (mean 3.84 hits)
#define OVFC 64       // LDS overflow list capacity
#define CNTSTR 16     // cnt_g stride in ints (64B: one cacheline per counter)

// order-preserving fp32 <-> u32 (strictly monotone for all non-NaN)
__device__ __forceinline__ unsigned fmap(float f) {
    unsigned u = __float_as_uint(f);
    return (u & 0x80000000u) ? ~u : (u | 0x80000000u);
}
__device__ __forceinline__ float funmap(unsigned u) {
    unsigned b = (u & 0x80000000u) ? (u ^ 0x80000000u) : ~u;
    return __uint_as_float(b);
}

// Exact reference IoU>0.5 test with division-free fast path.
// Reference: uni>0 && fdiv_rn(inter,uni) > 0.5.
// t = 0.5*uni is EXACT (uni >= ~1e-4 here, no denormals; *0.5 exact).
//  - inter <= t          => real q <= 0.5 => rounded q <= 0.5 => false (exact)
//  - inter >  t*(1+5e-7) => real q > 0.5*(1+2^-24) => rounded q > 0.5 => true (exact)
//  - else (band, rel width ~4e-7): evaluate the actual IEEE division.
__device__ __forceinline__ bool sup_test(float4 s, float sa, float4 c, float ca) {
    float y1 = fmaxf(s.x, c.x);
    float x1 = fmaxf(s.y, c.y);
    float y2 = fminf(s.z, c.z);
    float x2 = fminf(s.w, c.w);
    float dy = fmaxf(__fsub_rn(y2, y1), 0.f);
    float dx = fmaxf(__fsub_rn(x2, x1), 0.f);
    float inter = __fmul_rn(dy, dx);
    float uni = __fsub_rn(__fadd_rn(sa, ca), inter);
    if (!(uni > 0.f)) return false;
    float t = 0.5f * uni;                       // exact
    if (inter <= t) return false;               // q <= 0.5 exactly
    if (inter > __fmul_rn(t, 1.0000005f)) return true;  // q > 0.5 certainly
    return __fdiv_rn(inter, uni) > 0.5f;        // rare boundary: real division
}
__device__ __forceinline__ float box_area(float4 b) {
    return __fmul_rn(__fsub_rn(b.z, b.x), __fsub_rn(b.w, b.y));
}

// ---------------------------------------------------------------------------
// Kernel -1: zero counters (runtime fillBuffer is pathological for small bufs)
// ---------------------------------------------------------------------------
__global__ __launch_bounds__(NTH) void zero_k(int4* __restrict__ p, int n4) {
    int i = blockIdx.x * NTH + threadIdx.x;
    if (i < n4) p[i] = make_int4(0, 0, 0, 0);
}

__device__ __forceinline__ void bin_select(unsigned* hist, unsigned* gbuf,
                                           int* sh_g, int* sh_b, unsigned* sh_pb,
                                           int tid, unsigned need) {
    unsigned gs = 0;
#pragma unroll
    for (int q = 0; q < GRP; ++q) gs += hist[tid * GRP + q];
    gbuf[tid] = gs;
    __syncthreads();
    for (int off = 1; off < NTH; off <<= 1) {
        unsigned add = (tid >= off) ? gbuf[tid - off] : 0u;
        __syncthreads();
        gbuf[tid] += add;
        __syncthreads();
    }
    if (tid == 0) *sh_g = NTH - 1;
    __syncthreads();
    if (gbuf[tid] >= need && (tid == 0 || gbuf[tid - 1] < need)) *sh_g = tid;
    __syncthreads();
    if (tid == 0) {
        int g = *sh_g;
        unsigned acc = (g > 0) ? gbuf[g - 1] : 0u;
        int bs = g * GRP + (GRP - 1);
        unsigned pb = acc;
#pragma unroll
        for (int q = 0; q < GRP; ++q) {
            acc += hist[g * GRP + q];
            if (acc >= need) { bs = g * GRP + q; pb = acc; break; }
            pb = acc;
        }
        *sh_b = bs; *sh_pb = pb;
    }
    __syncthreads();
}

// bitonic sort descending of cand[0..M), zero-padded to pow2. Whole block.
__device__ __forceinline__ void sort_desc(unsigned long long* cand, int M, int tid) {
    int P = 1;
    while (P < M) P <<= 1;
    for (int i = M + tid; i < P; i += NTH) cand[i] = 0ull;
    __syncthreads();
    for (int kk = 2; kk <= P; kk <<= 1) {
        for (int jj = kk >> 1; jj > 0; jj >>= 1) {
            for (int i = tid; i < P; i += NTH) {
                int ixj = i ^ jj;
                if (ixj > i) {
                    unsigned long long a = cand[i], c = cand[ixj];
                    bool sw = ((i & kk) == 0) ? (a < c) : (a > c);
                    if (sw) { cand[i] = c; cand[ixj] = a; }
                }
            }
            __syncthreads();
        }
    }
}

// ---------------------------------------------------------------------------
// filter_k helper: route one hit into per-class LDS staging. Exact.
// ---------------------------------------------------------------------------
__device__ __forceinline__ void emit_hit(unsigned long long pk, int b, int n0,
                                         int* cnt_s, unsigned long long* ent,
                                         unsigned* ovf_meta,
                                         unsigned long long* ovf_key,
                                         int* sh_ovf, int* cnt_g) {
    unsigned ee = (unsigned)pk;
    int row = (int)ee / NCLSIN;
    int c = (int)ee - row * NCLSIN;
    if (c == 0) return;  // background
    unsigned i = (unsigned)(n0 + row);
    unsigned long long key = (pk & 0xFFFFFFFF00000000ull) | (0xFFFFFFFFu - i);
    int r = atomicAdd(&cnt_s[c], 1);
    if (r < KSL) {
        ent[c * KSL + r] = key;
    } else {
        int o = atomicAdd(sh_ovf, 1);
        if (o < OVFC) {
            ovf_meta[o] = ((unsigned)c << 16) | (unsigned)r;
            ovf_key[o] = key;
        } else {
            atomicAdd(&cnt_g[(b * NCLS + c - 1) * CNTSTR], CAP + 1);
        }
    }
}

// ---------------------------------------------------------------------------
// Kernel 0: stream scores once (2x float4/lane). Hits buffered in 4 per-lane
// registers, drained at end; >=5th hit spills to immediate path.
// ---------------------------------------------------------------------------
__global__ __launch_bounds__(NTH) void filter_k(const float* __restrict__ in,
                                                unsigned long long* __restrict__ cand_g,
                                                int* __restrict__ cnt_g) {
    __shared__ int cnt_s[NCLSIN];
    __shared__ int base_s[NCLSIN];
    __shared__ unsigned long long ent[NCLSIN * KSL];
    __shared__ unsigned ovf_meta[OVFC];
    __shared__ unsigned long long ovf_key[OVFC];
    __shared__ int sh_ovf;

    const int tid = threadIdx.x;
    const int n0 = blockIdx.x * BOXPB;
    const int b = blockIdx.y;
    const int NF4 = BOXPB * NCLSIN / 4;

    for (int i = tid; i < NCLSIN; i += NTH) cnt_s[i] = 0;
    if (tid == 0) sh_ovf = 0;
    __syncthreads();

    unsigned long long q0 = 0, q1 = 0, q2 = 0, q3 = 0;
    int lc = 0;

    const float4* src = (const float4*)(in + ((size_t)b * NBOX + n0) * NCLSIN);
    for (int i = tid; i < NF4; i += 2 * NTH) {
        float4 v1 = src[i];
        int i2 = i + NTH;
        bool has2 = i2 < NF4;
        float4 v2 = make_float4(0.f, 0.f, 0.f, 0.f);
        if (has2) v2 = src[i2];
        float mx1 = fmaxf(fmaxf(v1.x, v1.y), fmaxf(v1.z, v1.w));
        float mx2 = fmaxf(fmaxf(v2.x, v2.y), fmaxf(v2.z, v2.w));
        if (fmaxf(mx1, mx2) > T0) {
#pragma unroll
            for (int h = 0; h < 2; ++h) {
                float4 v = h ? v2 : v1;
                float mx = h ? mx2 : mx1;
                int eb = (h ? i2 : i) * 4;
                if (mx > T0) {
                    const float sv[4] = {v.x, v.y, v.z, v.w};
#pragma unroll
                    for (int qq = 0; qq < 4; ++qq) {
                        float s = sv[qq];
                        if (s > T0) {
                            unsigned long long pk =
                                ((unsigned long long)fmap(s) << 32) |
                                (unsigned)(eb + qq);
                            if (lc == 0) q0 = pk;
                            else if (lc == 1) q1 = pk;
                            else if (lc == 2) q2 = pk;
                            else if (lc == 3) q3 = pk;
                            else emit_hit(pk, b, n0, cnt_s, ent, ovf_meta,
                                          ovf_key, &sh_ovf, cnt_g);
                            ++lc;
                        }
                    }
                }
            }
        }
    }
    if (lc > 0) emit_hit(q0, b, n0, cnt_s, ent, ovf_meta, ovf_key, &sh_ovf, cnt_g);
    if (lc > 1) emit_hit(q1, b, n0, cnt_s, ent, ovf_meta, ovf_key, &sh_ovf, cnt_g);
    if (lc > 2) emit_hit(q2, b, n0, cnt_s, ent, ovf_meta, ovf_key, &sh_ovf, cnt_g);
    if (lc > 3) emit_hit(q3, b, n0, cnt_s, ent, ovf_meta, ovf_key, &sh_ovf, cnt_g);
    __syncthreads();

    if (tid >= 1 && tid < NCLSIN) {
        int c = tid;
        int n = cnt_s[c];
        int base = 0;
        if (n > 0) {
            int bc = b * NCLS + c - 1;
            base = atomicAdd(&cnt_g[bc * CNTSTR], n);
            int lim = n < KSL ? n : KSL;
            for (int j = 0; j < lim; ++j) {
                int pos = base + j;
                if (pos < CAP) cand_g[(size_t)bc * CAP + pos] = ent[c * KSL + j];
            }
        }
        base_s[c] = base;
    }
    __syncthreads();

    int no = sh_ovf < OVFC ? sh_ovf : OVFC;
    for (int o = tid; o < no; o += NTH) {
        unsigned m = ovf_meta[o];
        int c = (int)(m >> 16);
        int r = (int)(m & 0xFFFFu);
        int bc = b * NCLS + c - 1;
        int pos = base_s[c] + r;
        if (pos < CAP) cand_g[(size_t)bc * CAP + pos] = ovf_key[o];
    }
}

// ---------------------------------------------------------------------------
// Greedy walk, wave 0 only. Selected boxes live in 2 register slots per lane.
// walk_fast: software-pipelined (prefetch m+1 before ballot of m).
// ---------------------------------------------------------------------------
__device__ __forceinline__ void walk_fast(
    const unsigned long long* cand, const float4* candbox, int M,
    float4& sel0, float4& sel1, float& sa0, float& sa1,
    float& ss0, float& ss1, int& nsel, int* sh_nsel, int tid) {
    if (tid < 64) {
        unsigned long long key_c = cand[0];
        float4 bx_c = candbox[0];
        for (int m = 0; m < M; ++m) {
            int mn = (m + 1 < M) ? m + 1 : m;
            unsigned long long key_n = cand[mn];  // prefetch next (hides LDS lat)
            float4 bx_n = candbox[mn];
            float ca = box_area(bx_c);
            bool sup = false;
            if (tid < nsel) sup = sup_test(sel0, sa0, bx_c, ca);
            if (tid + 64 < nsel) sup = sup || sup_test(sel1, sa1, bx_c, ca);
            if (!__any(sup)) {
                if (tid == nsel) { sel0 = bx_c; sa0 = ca; ss0 = funmap((unsigned)(key_c >> 32)); }
                if (tid == nsel - 64) { sel1 = bx_c; sa1 = ca; ss1 = funmap((unsigned)(key_c >> 32)); }
                nsel++;
                if (nsel >= MAXSEL) break;
            }
            key_c = key_n;
            bx_c = bx_n;
        }
        if (tid == 0) *sh_nsel = nsel;
    }
    __syncthreads();
    nsel = *sh_nsel;
    __syncthreads();
}

// walk_slow: unpipelined, global-fetch fallback beyond CBCAP (rare paths)
__device__ __forceinline__ void walk_slow(
    const unsigned long long* cand, int from, int to,
    const float4* __restrict__ bbase, const float4* candbox,
    float4& sel0, float4& sel1, float& sa0, float& sa1,
    float& ss0, float& ss1, int& nsel, int* sh_nsel, int tid) {
    if (tid < 64) {
        for (int m = from; m < to && nsel < MAXSEL; ++m) {
            unsigned long long key = cand[m];
            float4 bx = (m < CBCAP) ? candbox[m]
                                    : bbase[(int)(0xFFFFFFFFu - (unsigned)key)];
            float ca = box_area(bx);
            bool sup = false;
            if (tid < nsel) sup = sup_test(sel0, sa0, bx, ca);
            if (tid + 64 < nsel) sup = sup || sup_test(sel1, sa1, bx, ca);
            if (!__any(sup)) {
                if (tid == nsel) { sel0 = bx; sa0 = ca; ss0 = funmap((unsigned)(key >> 32)); }
                if (tid == nsel - 64) { sel1 = bx; sa1 = ca; ss1 = funmap((unsigned)(key >> 32)); }
                nsel++;
            }
        }
        if (tid == 0) *sh_nsel = nsel;
    }
    __syncthreads();
    nsel = *sh_nsel;
    __syncthreads();
}

// ---------------------------------------------------------------------------
// Kernel 1: one block per (batch, class). Sort band -> pipelined register
// walk. Exact refill via adaptive radix-select over raw strided scores.
// ---------------------------------------------------------------------------
__global__ __launch_bounds__(NTH) void nms_k(
    const unsigned long long* __restrict__ cand_g,
    const int* __restrict__ cnt_g,
    const float* __restrict__ scores_raw,
    const float4* __restrict__ boxes,
    float* __restrict__ ws_sc, float* __restrict__ ws_bx, int use_band) {
    __shared__ unsigned long long cand[CAP];   // 8 KB
    __shared__ float4 candbox[CBCAP];          // 6 KB (aliased as hist in fallback)
    __shared__ unsigned gbuf[NTH];             // 1 KB
    __shared__ unsigned sh_kmax, sh_pb;
    __shared__ int sh_E, sh_g, sh_b, sh_cnt, sh_nsel;
    unsigned* hist = (unsigned*)candbox;  // candbox dead while hist live

    const int tid = threadIdx.x;
    const int c0 = blockIdx.x;
    const int b = blockIdx.y;
    const int bc = b * NCLS + c0;
    const float* sraw = scores_raw + (size_t)b * NBOX * NCLSIN + (c0 + 1);
    const float4* bbase = boxes + (size_t)b * NBOX;

    float4 sel0 = make_float4(0.f, 0.f, 0.f, 0.f);
    float4 sel1 = make_float4(0.f, 0.f, 0.f, 0.f);
    float sa0 = 0.f, sa1 = 0.f, ss0 = 0.f, ss1 = 0.f;
    int nsel = 0;
    unsigned long long lastk = ~0ull;

    if (use_band) {
        const int C = cnt_g[bc * CNTSTR];
        if (C > 0 && C <= CAP) {
            for (int i = tid; i < C; i += NTH)
                cand[i] = cand_g[(size_t)bc * CAP + i];
            sort_desc(cand, C, tid);
            const int PBX = C < CBCAP ? C : CBCAP;
            for (int i = tid; i < PBX; i += NTH)
                candbox[i] = bbase[(int)(0xFFFFFFFFu - (unsigned)cand[i])];
            __syncthreads();
            if (C <= CBCAP)
                walk_fast(cand, candbox, C, sel0, sel1, sa0, sa1,
                          ss0, ss1, nsel, &sh_nsel, tid);
            else
                walk_slow(cand, 0, C, bbase, candbox, sel0, sel1, sa0, sa1,
                          ss0, ss1, nsel, &sh_nsel, tid);
            lastk = cand[C - 1];  // smallest examined key
        }
        // C==0 or C>CAP: lastk stays ~0 -> exact full fallback below
    }

    while (nsel < MAXSEL) {
        // ---- eligible count + max key (keys strictly below lastk) ----
        unsigned km = 0, ce = 0;
        for (int i = tid; i < NBOX; i += NTH) {
            float s = sraw[(size_t)i * NCLSIN];
            unsigned k = (s > 0.3f) ? fmap(s) : 0u;
            if (k) {
                unsigned long long key =
                    ((unsigned long long)k << 32) | (0xFFFFFFFFu - (unsigned)i);
                if (key < lastk) { ce++; km = km > k ? km : k; }
            }
        }
#pragma unroll
        for (int off = 32; off > 0; off >>= 1) {
            unsigned o = (unsigned)__shfl_xor((int)km, off, 64);
            km = km > o ? km : o;
            ce += (unsigned)__shfl_xor((int)ce, off, 64);
        }
        if ((tid & 63) == 0) { gbuf[tid >> 6] = km; gbuf[8 + (tid >> 6)] = ce; }
        __syncthreads();
        if (tid == 0) {
            unsigned m2 = 0, c2 = 0;
            for (int w = 0; w < NTH / 64; ++w) {
                m2 = m2 > gbuf[w] ? m2 : gbuf[w];
                c2 += gbuf[8 + w];
            }
            sh_kmax = m2; sh_E = (int)c2;
        }
        __syncthreads();
        const int E = sh_E;
        const unsigned kmax = sh_kmax;
        if (E == 0) break;

        unsigned thr = 1u;
        if (E > TSEL) {
            for (int shift = 8;; shift += 4) {
                for (int i = tid; i < BINS; i += NTH) hist[i] = 0u;
                __syncthreads();
                for (int i = tid; i < NBOX; i += NTH) {
                    float s = sraw[(size_t)i * NCLSIN];
                    unsigned k = (s > 0.3f) ? fmap(s) : 0u;
                    if (k) {
                        unsigned long long key =
                            ((unsigned long long)k << 32) | (0xFFFFFFFFu - (unsigned)i);
                        if (key < lastk) {
                            unsigned bin = (kmax - k) >> shift;
                            if (bin < BINS - 1) atomicAdd(&hist[bin], 1u);
                        }
                    }
                }
                __syncthreads();
                bin_select(hist, gbuf, &sh_g, &sh_b, &sh_pb, tid, (unsigned)TSEL);
                if (sh_b < BINS - 1) {
                    long long t = (long long)kmax - ((long long)(sh_b + 1) << shift) + 1;
                    thr = (t < 1) ? 1u : (unsigned)t;
                    break;
                }
            }
        }

        if (tid == 0) sh_cnt = 0;
        __syncthreads();
        for (int i = tid; i < NBOX; i += NTH) {
            float s = sraw[(size_t)i * NCLSIN];
            unsigned k = (s > 0.3f) ? fmap(s) : 0u;
            if (k >= thr) {
                unsigned long long key =
                    ((unsigned long long)k << 32) | (0xFFFFFFFFu - (unsigned)i);
                if (key < lastk) {
                    int pos = atomicAdd(&sh_cnt, 1);
                    if (pos < CAP) cand[pos] = key;
                }
            }
        }
        __syncthreads();
        const int M = sh_cnt < CAP ? sh_cnt : CAP;

        sort_desc(cand, M, tid);
        const int PBX = M < CBCAP ? M : CBCAP;
        for (int i = tid; i < PBX; i += NTH)
            candbox[i] = bbase[(int)(0xFFFFFFFFu - (unsigned)cand[i])];
        __syncthreads();
        walk_slow(cand, 0, M, bbase, candbox, sel0, sel1, sa0, sa1,
                  ss0, ss1, nsel, &sh_nsel, tid);
        if (nsel >= MAXSEL || E <= M) break;
        lastk = cand[M - 1];
        __syncthreads();
    }

    // ---- outputs: selections in greedy order, zero-padded ----
    if (tid < 64) {
        float* scp = ws_sc + (size_t)bc * MAXSEL;
        float4* bxp = (float4*)(ws_bx + (size_t)bc * MAXSEL * 4);
        {
            bool v = tid < nsel;
            scp[tid] = v ? ss0 : 0.f;
            bxp[tid] = v ? sel0 : make_float4(0.f, 0.f, 0.f, 0.f);
        }
        int j1 = tid + 64;
        if (j1 < MAXSEL) {
            bool v = j1 < nsel;
            scp[j1] = v ? ss1 : 0.f;
            bxp[j1] = v ? sel1 : make_float4(0.f, 0.f, 0.f, 0.f);
        }
    }
}

// ---------------------------------------------------------------------------
// Kernel 2: one block per batch: stable top-200 of 9000 via radix-select+sort.
// ---------------------------------------------------------------------------
__global__ __launch_bounds__(NTH) void topk_k(const float* __restrict__ ws_sc,
                                              const float* __restrict__ ws_bx,
                                              float* __restrict__ out_sc,
                                              float* __restrict__ out_bx) {
    __shared__ unsigned hist[BINS];
    __shared__ unsigned gbuf[NTH];
    __shared__ unsigned long long cand[CAP];
    __shared__ unsigned sh_kmax, sh_pb;
    __shared__ int sh_E, sh_g, sh_b, sh_cnt;

    const int tid = threadIdx.x;
    const int b = blockIdx.x;
    const int NF = NCLS * MAXSEL;  // 9000
    const float* sp = ws_sc + (size_t)b * NF;

    unsigned km = 0, ce = 0;
    for (int f = tid; f < NF; f += NTH) {
        unsigned k = __float_as_uint(sp[f]);
        if (k) { ce++; km = km > k ? km : k; }
    }
#pragma unroll
    for (int off = 32; off > 0; off >>= 1) {
        unsigned o = (unsigned)__shfl_xor((int)km, off, 64);
        km = km > o ? km : o;
        ce += (unsigned)__shfl_xor((int)ce, off, 64);
    }
    if ((tid & 63) == 0) { gbuf[tid >> 6] = km; gbuf[8 + (tid >> 6)] = ce; }
    __syncthreads();
    if (tid == 0) {
        unsigned m2 = 0, c2 = 0;
        for (int w = 0; w < NTH / 64; ++w) {
            m2 = m2 > gbuf[w] ? m2 : gbuf[w];
            c2 += gbuf[8 + w];
        }
        sh_kmax = m2; sh_E = (int)c2;
    }
    __syncthreads();
    const int E = sh_E;
    const unsigned kmax = sh_kmax;

    unsigned thr = 1u;
    if (E > TOPK) {
        for (int shift = 8;; shift += 4) {
            for (int i = tid; i < BINS; i += NTH) hist[i] = 0u;
            __syncthreads();
            for (int f = tid; f < NF; f += NTH) {
                unsigned k = __float_as_uint(sp[f]);
                if (k) {
                    unsigned bin = (kmax - k) >> shift;
                    if (bin < BINS - 1) atomicAdd(&hist[bin], 1u);
                }
            }
            __syncthreads();
            bin_select(hist, gbuf, &sh_g, &sh_b, &sh_pb, tid, (unsigned)TOPK);
            if (sh_b < BINS - 1) {
                long long t = (long long)kmax - ((long long)(sh_b + 1) << shift) + 1;
                thr = (t < 1) ? 1u : (unsigned)t;
                break;
            }
        }
    }

    if (tid == 0) sh_cnt = 0;
    __syncthreads();
    for (int f = tid; f < NF; f += NTH) {
        unsigned k = __float_as_uint(sp[f]);
        if (k >= thr) {
            int pos = atomicAdd(&sh_cnt, 1);
            if (pos < CAP)
                cand[pos] = ((unsigned long long)k << 32) | (0xFFFFFFFFu - (unsigned)f);
        }
    }
    __syncthreads();
    int M = sh_cnt < CAP ? sh_cnt : CAP;

    if (M < TOPK) {
        int lim = M + TOPK;
        if (lim > NF) lim = NF;
        for (int f = tid; f < lim; f += NTH) {
            unsigned k = __float_as_uint(sp[f]);
            if (k == 0) {
                int pos = atomicAdd(&sh_cnt, 1);
                if (pos < CAP)
                    cand[pos] = (unsigned long long)(0xFFFFFFFFu - (unsigned)f);
            }
        }
        __syncthreads();
        M = sh_cnt < CAP ? sh_cnt : CAP;
    }

    sort_desc(cand, M, tid);

    for (int k = tid; k < TOPK; k += NTH) {
        float cls = 0.f, s = 0.f;
        float4 bx = make_float4(0.f, 0.f, 0.f, 0.f);
        if (k < M) {
            unsigned long long key = cand[k];
            unsigned f = 0xFFFFFFFFu - (unsigned)key;
            s = __uint_as_float((unsigned)(key >> 32));
            cls = (s > 0.f) ? (float)(f / MAXSEL + 1) : 0.f;
            bx = *(const float4*)(ws_bx + ((size_t)b * NF + f) * 4);
        }
        out_sc[((size_t)b * TOPK + k) * 2 + 0] = cls;
        out_sc[((size_t)b * TOPK + k) * 2 + 1] = s;
        ((float4*)out_bx)[(size_t)b * TOPK + k] = bx;
    }
}

// ---------------------------------------------------------------------------
extern "C" void kernel_launch(void* const* d_in, const int* in_sizes, int n_in,
                              void* d_out, int out_size, void* d_ws, size_t ws_size,
                              hipStream_t stream) {
    const float* scores = (const float*)d_in[0];
    const float4* boxes = (const float4*)d_in[1];
    float* out = (float*)d_out;

    const int B = in_sizes[1] / (NBOX * 4);
    const int NBC = B * NCLS;

    // ws layout: cnt [NBC * CNTSTR ints] | cand [NBC*CAP u64] | sc | bx
    size_t off_cand = ((size_t)NBC * CNTSTR * 4 + 15) & ~(size_t)15;
    size_t off_sc = off_cand + (size_t)NBC * CAP * 8;
    size_t off_bx = off_sc + (size_t)NBC * MAXSEL * 4;
    size_t need = off_bx + (size_t)NBC * MAXSEL * 16;

    char* ws = (char*)d_ws;
    bool use_band = ws_size >= need;

    int* cnt_g;
    unsigned long long* cand_g;
    float *ws_sc, *ws_bx;
    if (use_band) {
        cnt_g = (int*)ws;
        cand_g = (unsigned long long*)(ws + off_cand);
        ws_sc = (float*)(ws + off_sc);
        ws_bx = (float*)(ws + off_bx);
    } else {
        cnt_g = (int*)ws;                  // unused
        cand_g = (unsigned long long*)ws;  // unused
        ws_sc = (float*)ws;
        ws_bx = ws_sc + (size_t)NBC * MAXSEL;
    }

    if (use_band) {
        int n4 = NBC * CNTSTR / 4;
        zero_k<<<(n4 + NTH - 1) / NTH, NTH, 0, stream>>>((int4*)cnt_g, n4);
        filter_k<<<dim3(NBOX / BOXPB, B), NTH, 0, stream>>>(scores, cand_g, cnt_g);
    }
    nms_k<<<dim3(NCLS, B), NTH, 0, stream>>>(cand_g, cnt_g, scores, boxes,
                                             ws_sc, ws_bx, use_band ? 1 : 0);
    topk_k<<<B, NTH, 0, stream>>>(ws_sc, ws_bx, out, out + (size_t)B * TOPK * 2);
}

// Round 12
// 113.995 us; speedup vs baseline: 1.2165x; 1.1507x over previous
//
#include <hip/hip_runtime.h>

#define NTH 256
#define NBOX 16384
#define NCLSIN 91
#define NCLS 90
#define MAXSEL 100
#define TOPK 200
#define TSEL 256      // fallback radix-select size
#define CAP 1024      // candidate list stride per (b,c)
#define CANDL 512     // LDS band capacity (reg-sort covers <=256)
#define CBCAP 256     // prefetched candidate boxes
#define BINS 1024
#define GRP 4         // BINS / NTH
#define T0 0.989f     // band threshold: E[C]=180, sigma 13.4; fallbacks guard
#define BOXPB 256     // boxes per filter block
#define KSL 16        // per-class LDS slots per filter block (mean 2.8 hits)
#define OVFC 64       // LDS overflow list capacity
#define CNTSTR 16     // cnt_g stride in ints (64B per counter)

// order-preserving fp32 <-> u32 (strictly monotone for all non-NaN)
__device__ __forceinline__ unsigned fmap(float f) {
    unsigned u = __float_as_uint(f);
    return (u & 0x80000000u) ? ~u : (u | 0x80000000u);
}
__device__ __forceinline__ float funmap(unsigned u) {
    unsigned b = (u & 0x80000000u) ? (u ^ 0x80000000u) : ~u;
    return __uint_as_float(b);
}
__device__ __forceinline__ unsigned long long shfl_xor_u64(unsigned long long v, int mask) {
    unsigned lo = (unsigned)(v & 0xFFFFFFFFull);
    unsigned hi = (unsigned)(v >> 32);
    lo = __shfl_xor(lo, mask, 64);
    hi = __shfl_xor(hi, mask, 64);
    return ((unsigned long long)hi << 32) | (unsigned long long)lo;
}

// Exact reference IoU>0.5 with division-free fast path (r11, verified exact):
//  t = 0.5*uni exact; inter<=t => false; inter>t*(1+5e-7) => true;
//  razor-thin band => actual IEEE division.
__device__ __forceinline__ bool sup_test(float4 s, float sa, float4 c, float ca) {
    float y1 = fmaxf(s.x, c.x);
    float x1 = fmaxf(s.y, c.y);
    float y2 = fminf(s.z, c.z);
    float x2 = fminf(s.w, c.w);
    float dy = fmaxf(__fsub_rn(y2, y1), 0.f);
    float dx = fmaxf(__fsub_rn(x2, x1), 0.f);
    float inter = __fmul_rn(dy, dx);
    float uni = __fsub_rn(__fadd_rn(sa, ca), inter);
    if (!(uni > 0.f)) return false;
    float t = 0.5f * uni;
    if (inter <= t) return false;
    if (inter > __fmul_rn(t, 1.0000005f)) return true;
    return __fdiv_rn(inter, uni) > 0.5f;
}
__device__ __forceinline__ float box_area(float4 b) {
    return __fmul_rn(__fsub_rn(b.z, b.x), __fsub_rn(b.w, b.y));
}

// ---------------------------------------------------------------------------
__global__ __launch_bounds__(NTH) void zero_k(int4* __restrict__ p, int n4) {
    int i = blockIdx.x * NTH + threadIdx.x;
    if (i < n4) p[i] = make_int4(0, 0, 0, 0);
}

__device__ __forceinline__ void bin_select(unsigned* hist, unsigned* gbuf,
                                           int* sh_g, int* sh_b, unsigned* sh_pb,
                                           int tid, unsigned need) {
    unsigned gs = 0;
#pragma unroll
    for (int q = 0; q < GRP; ++q) gs += hist[tid * GRP + q];
    gbuf[tid] = gs;
    __syncthreads();
    for (int off = 1; off < NTH; off <<= 1) {
        unsigned add = (tid >= off) ? gbuf[tid - off] : 0u;
        __syncthreads();
        gbuf[tid] += add;
        __syncthreads();
    }
    if (tid == 0) *sh_g = NTH - 1;
    __syncthreads();
    if (gbuf[tid] >= need && (tid == 0 || gbuf[tid - 1] < need)) *sh_g = tid;
    __syncthreads();
    if (tid == 0) {
        int g = *sh_g;
        unsigned acc = (g > 0) ? gbuf[g - 1] : 0u;
        int bs = g * GRP + (GRP - 1);
        unsigned pb = acc;
#pragma unroll
        for (int q = 0; q < GRP; ++q) {
            acc += hist[g * GRP + q];
            if (acc >= need) { bs = g * GRP + q; pb = acc; break; }
            pb = acc;
        }
        *sh_b = bs; *sh_pb = pb;
    }
    __syncthreads();
}

// LDS bitonic sort descending (fallback path for 256 < C <= CANDL)
__device__ __forceinline__ void sort_desc(unsigned long long* cand, int M, int tid) {
    int P = 1;
    while (P < M) P <<= 1;
    for (int i = M + tid; i < P; i += NTH) cand[i] = 0ull;
    __syncthreads();
    for (int kk = 2; kk <= P; kk <<= 1) {
        for (int jj = kk >> 1; jj > 0; jj >>= 1) {
            for (int i = tid; i < P; i += NTH) {
                int ixj = i ^ jj;
                if (ixj > i) {
                    unsigned long long a = cand[i], c = cand[ixj];
                    bool sw = ((i & kk) == 0) ? (a < c) : (a > c);
                    if (sw) { cand[i] = c; cand[ixj] = a; }
                }
            }
            __syncthreads();
        }
    }
}

// ---------------------------------------------------------------------------
// filter_k helper: route one hit into per-class LDS staging. Exact.
// ---------------------------------------------------------------------------
__device__ __forceinline__ void emit_hit(unsigned long long pk, int b, int n0,
                                         int* cnt_s, unsigned long long* ent,
                                         unsigned* ovf_meta,
                                         unsigned long long* ovf_key,
                                         int* sh_ovf, int* cnt_g) {
    unsigned ee = (unsigned)pk;
    int row = (int)ee / NCLSIN;
    int c = (int)ee - row * NCLSIN;
    if (c == 0) return;  // background
    unsigned i = (unsigned)(n0 + row);
    unsigned long long key = (pk & 0xFFFFFFFF00000000ull) | (0xFFFFFFFFu - i);
    int r = atomicAdd(&cnt_s[c], 1);
    if (r < KSL) {
        ent[c * KSL + r] = key;
    } else {
        int o = atomicAdd(sh_ovf, 1);
        if (o < OVFC) {
            ovf_meta[o] = ((unsigned)c << 16) | (unsigned)r;
            ovf_key[o] = key;
        } else {
            atomicAdd(&cnt_g[(b * NCLS + c - 1) * CNTSTR], CAP + 1);
        }
    }
}

// ---------------------------------------------------------------------------
// Kernel 0: stream scores once (2x float4/lane). Hits buffered in 4 per-lane
// registers, drained at end; >=5th hit spills to immediate path.
// ---------------------------------------------------------------------------
__global__ __launch_bounds__(NTH) void filter_k(const float* __restrict__ in,
                                                unsigned long long* __restrict__ cand_g,
                                                int* __restrict__ cnt_g) {
    __shared__ int cnt_s[NCLSIN];
    __shared__ int base_s[NCLSIN];
    __shared__ unsigned long long ent[NCLSIN * KSL];
    __shared__ unsigned ovf_meta[OVFC];
    __shared__ unsigned long long ovf_key[OVFC];
    __shared__ int sh_ovf;

    const int tid = threadIdx.x;
    const int n0 = blockIdx.x * BOXPB;
    const int b = blockIdx.y;
    const int NF4 = BOXPB * NCLSIN / 4;

    for (int i = tid; i < NCLSIN; i += NTH) cnt_s[i] = 0;
    if (tid == 0) sh_ovf = 0;
    __syncthreads();

    unsigned long long q0 = 0, q1 = 0, q2 = 0, q3 = 0;
    int lc = 0;

    const float4* src = (const float4*)(in + ((size_t)b * NBOX + n0) * NCLSIN);
    for (int i = tid; i < NF4; i += 2 * NTH) {
        float4 v1 = src[i];
        int i2 = i + NTH;
        bool has2 = i2 < NF4;
        float4 v2 = make_float4(0.f, 0.f, 0.f, 0.f);
        if (has2) v2 = src[i2];
        float mx1 = fmaxf(fmaxf(v1.x, v1.y), fmaxf(v1.z, v1.w));
        float mx2 = fmaxf(fmaxf(v2.x, v2.y), fmaxf(v2.z, v2.w));
        if (fmaxf(mx1, mx2) > T0) {
#pragma unroll
            for (int h = 0; h < 2; ++h) {
                float4 v = h ? v2 : v1;
                float mx = h ? mx2 : mx1;
                int eb = (h ? i2 : i) * 4;
                if (mx > T0) {
                    const float sv[4] = {v.x, v.y, v.z, v.w};
#pragma unroll
                    for (int qq = 0; qq < 4; ++qq) {
                        float s = sv[qq];
                        if (s > T0) {
                            unsigned long long pk =
                                ((unsigned long long)fmap(s) << 32) |
                                (unsigned)(eb + qq);
                            if (lc == 0) q0 = pk;
                            else if (lc == 1) q1 = pk;
                            else if (lc == 2) q2 = pk;
                            else if (lc == 3) q3 = pk;
                            else emit_hit(pk, b, n0, cnt_s, ent, ovf_meta,
                                          ovf_key, &sh_ovf, cnt_g);
                            ++lc;
                        }
                    }
                }
            }
        }
    }
    if (lc > 0) emit_hit(q0, b, n0, cnt_s, ent, ovf_meta, ovf_key, &sh_ovf, cnt_g);
    if (lc > 1) emit_hit(q1, b, n0, cnt_s, ent, ovf_meta, ovf_key, &sh_ovf, cnt_g);
    if (lc > 2) emit_hit(q2, b, n0, cnt_s, ent, ovf_meta, ovf_key, &sh_ovf, cnt_g);
    if (lc > 3) emit_hit(q3, b, n0, cnt_s, ent, ovf_meta, ovf_key, &sh_ovf, cnt_g);
    __syncthreads();

    if (tid >= 1 && tid < NCLSIN) {
        int c = tid;
        int n = cnt_s[c];
        int base = 0;
        if (n > 0) {
            int bc = b * NCLS + c - 1;
            base = atomicAdd(&cnt_g[bc * CNTSTR], n);
            int lim = n < KSL ? n : KSL;
            for (int j = 0; j < lim; ++j) {
                int pos = base + j;
                if (pos < CAP) cand_g[(size_t)bc * CAP + pos] = ent[c * KSL + j];
            }
        }
        base_s[c] = base;
    }
    __syncthreads();

    int no = sh_ovf < OVFC ? sh_ovf : OVFC;
    for (int o = tid; o < no; o += NTH) {
        unsigned m = ovf_meta[o];
        int c = (int)(m >> 16);
        int r = (int)(m & 0xFFFFu);
        int bc = b * NCLS + c - 1;
        int pos = base_s[c] + r;
        if (pos < CAP) cand_g[(size_t)bc * CAP + pos] = ovf_key[o];
    }
}

// ---------------------------------------------------------------------------
// Greedy walk, wave 0 only. Selected boxes in 2 register slots per lane.
// ---------------------------------------------------------------------------
__device__ __forceinline__ void walk_fast(
    const unsigned long long* cand, const float4* candbox, int M,
    float4& sel0, float4& sel1, float& sa0, float& sa1,
    float& ss0, float& ss1, int& nsel, int* sh_nsel, int tid) {
    if (tid < 64) {
        unsigned long long key_c = cand[0];
        float4 bx_c = candbox[0];
        for (int m = 0; m < M; ++m) {
            int mn = (m + 1 < M) ? m + 1 : m;
            unsigned long long key_n = cand[mn];
            float4 bx_n = candbox[mn];
            float ca = box_area(bx_c);
            bool sup = false;
            if (tid < nsel) sup = sup_test(sel0, sa0, bx_c, ca);
            if (tid + 64 < nsel) sup = sup || sup_test(sel1, sa1, bx_c, ca);
            if (!__any(sup)) {
                if (tid == nsel) { sel0 = bx_c; sa0 = ca; ss0 = funmap((unsigned)(key_c >> 32)); }
                if (tid == nsel - 64) { sel1 = bx_c; sa1 = ca; ss1 = funmap((unsigned)(key_c >> 32)); }
                nsel++;
                if (nsel >= MAXSEL) break;
            }
            key_c = key_n;
            bx_c = bx_n;
        }
        if (tid == 0) *sh_nsel = nsel;
    }
    __syncthreads();
    nsel = *sh_nsel;
    __syncthreads();
}

__device__ __forceinline__ void walk_slow(
    const unsigned long long* cand, int from, int to,
    const float4* __restrict__ bbase, const float4* candbox,
    float4& sel0, float4& sel1, float& sa0, float& sa1,
    float& ss0, float& ss1, int& nsel, int* sh_nsel, int tid) {
    if (tid < 64) {
        for (int m = from; m < to && nsel < MAXSEL; ++m) {
            unsigned long long key = cand[m];
            float4 bx = (m < CBCAP) ? candbox[m]
                                    : bbase[(int)(0xFFFFFFFFu - (unsigned)key)];
            float ca = box_area(bx);
            bool sup = false;
            if (tid < nsel) sup = sup_test(sel0, sa0, bx, ca);
            if (tid + 64 < nsel) sup = sup || sup_test(sel1, sa1, bx, ca);
            if (!__any(sup)) {
                if (tid == nsel) { sel0 = bx; sa0 = ca; ss0 = funmap((unsigned)(key >> 32)); }
                if (tid == nsel - 64) { sel1 = bx; sa1 = ca; ss1 = funmap((unsigned)(key >> 32)); }
                nsel++;
            }
        }
        if (tid == 0) *sh_nsel = nsel;
    }
    __syncthreads();
    nsel = *sh_nsel;
    __syncthreads();
}

// ---------------------------------------------------------------------------
// Kernel 1: one block per (batch, class). REGISTER bitonic sort via shfl_xor
// (33 intra-wave steps, only 3 LDS/barrier steps) for C<=256 (5-sigma case);
// LDS bitonic for 256<C<=512; adaptive radix refill below band. Exact.
// ---------------------------------------------------------------------------
__global__ __launch_bounds__(NTH) void nms_k(
    const unsigned long long* __restrict__ cand_g,
    const int* __restrict__ cnt_g,
    const float* __restrict__ scores_raw,
    const float4* __restrict__ boxes,
    float* __restrict__ ws_sc, float* __restrict__ ws_bx, int use_band) {
    __shared__ unsigned long long cand[CANDL];  // 4 KB
    __shared__ float4 candbox[CBCAP];           // 4 KB (aliased as hist in fallback)
    __shared__ unsigned gbuf[NTH];              // 1 KB
    __shared__ unsigned sh_kmax, sh_pb;
    __shared__ int sh_E, sh_g, sh_b, sh_cnt, sh_nsel;
    unsigned* hist = (unsigned*)candbox;  // candbox dead while hist live

    const int tid = threadIdx.x;
    const int c0 = blockIdx.x;
    const int b = blockIdx.y;
    const int bc = b * NCLS + c0;
    const float* sraw = scores_raw + (size_t)b * NBOX * NCLSIN + (c0 + 1);
    const float4* bbase = boxes + (size_t)b * NBOX;

    float4 sel0 = make_float4(0.f, 0.f, 0.f, 0.f);
    float4 sel1 = make_float4(0.f, 0.f, 0.f, 0.f);
    float sa0 = 0.f, sa1 = 0.f, ss0 = 0.f, ss1 = 0.f;
    int nsel = 0;
    unsigned long long lastk = ~0ull;

    if (use_band) {
        const int C = cnt_g[bc * CNTSTR];
        if (C > 0 && C <= CANDL) {
            if (C <= 256) {
                // ---- register bitonic, descending; pad 0 (keys are > 0) ----
                unsigned long long v =
                    (tid < C) ? cand_g[(size_t)bc * CAP + tid] : 0ull;
#pragma unroll
                for (int kk = 2; kk <= 256; kk <<= 1) {
#pragma unroll
                    for (int jj = kk >> 1; jj > 0; jj >>= 1) {
                        unsigned long long o;
                        if (jj >= 64) {  // cross-wave: via LDS (3 steps total)
                            cand[tid] = v;
                            __syncthreads();
                            o = cand[tid ^ jj];
                            __syncthreads();
                        } else {
                            o = shfl_xor_u64(v, jj);
                        }
                        bool lower = (tid & jj) == 0;
                        bool desc = (tid & kk) == 0;
                        v = (lower == desc) ? (v > o ? v : o) : (v < o ? v : o);
                    }
                }
                cand[tid] = v;
                __syncthreads();
            } else {
                for (int i = tid; i < C; i += NTH)
                    cand[i] = cand_g[(size_t)bc * CAP + i];
                sort_desc(cand, C, tid);
            }
            const int PBX = C < CBCAP ? C : CBCAP;
            for (int i = tid; i < PBX; i += NTH)
                candbox[i] = bbase[(int)(0xFFFFFFFFu - (unsigned)cand[i])];
            __syncthreads();
            if (C <= CBCAP)
                walk_fast(cand, candbox, C, sel0, sel1, sa0, sa1,
                          ss0, ss1, nsel, &sh_nsel, tid);
            else
                walk_slow(cand, 0, C, bbase, candbox, sel0, sel1, sa0, sa1,
                          ss0, ss1, nsel, &sh_nsel, tid);
            lastk = cand[C - 1];
        }
        // C==0 or C>CANDL: lastk stays ~0 -> exact full fallback below
    }

    while (nsel < MAXSEL) {
        // ---- eligible count + max key (keys strictly below lastk) ----
        unsigned km = 0, ce = 0;
        for (int i = tid; i < NBOX; i += NTH) {
            float s = sraw[(size_t)i * NCLSIN];
            unsigned k = (s > 0.3f) ? fmap(s) : 0u;
            if (k) {
                unsigned long long key =
                    ((unsigned long long)k << 32) | (0xFFFFFFFFu - (unsigned)i);
                if (key < lastk) { ce++; km = km > k ? km : k; }
            }
        }
#pragma unroll
        for (int off = 32; off > 0; off >>= 1) {
            unsigned o = (unsigned)__shfl_xor((int)km, off, 64);
            km = km > o ? km : o;
            ce += (unsigned)__shfl_xor((int)ce, off, 64);
        }
        if ((tid & 63) == 0) { gbuf[tid >> 6] = km; gbuf[8 + (tid >> 6)] = ce; }
        __syncthreads();
        if (tid == 0) {
            unsigned m2 = 0, c2 = 0;
            for (int w = 0; w < NTH / 64; ++w) {
                m2 = m2 > gbuf[w] ? m2 : gbuf[w];
                c2 += gbuf[8 + w];
            }
            sh_kmax = m2; sh_E = (int)c2;
        }
        __syncthreads();
        const int E = sh_E;
        const unsigned kmax = sh_kmax;
        if (E == 0) break;

        unsigned thr = 1u;
        if (E > TSEL) {
            for (int shift = 8;; shift += 4) {
                for (int i = tid; i < BINS; i += NTH) hist[i] = 0u;
                __syncthreads();
                for (int i = tid; i < NBOX; i += NTH) {
                    float s = sraw[(size_t)i * NCLSIN];
                    unsigned k = (s > 0.3f) ? fmap(s) : 0u;
                    if (k) {
                        unsigned long long key =
                            ((unsigned long long)k << 32) | (0xFFFFFFFFu - (unsigned)i);
                        if (key < lastk) {
                            unsigned bin = (kmax - k) >> shift;
                            if (bin < BINS - 1) atomicAdd(&hist[bin], 1u);
                        }
                    }
                }
                __syncthreads();
                bin_select(hist, gbuf, &sh_g, &sh_b, &sh_pb, tid, (unsigned)TSEL);
                if (sh_b < BINS - 1) {
                    long long t = (long long)kmax - ((long long)(sh_b + 1) << shift) + 1;
                    thr = (t < 1) ? 1u : (unsigned)t;
                    break;
                }
            }
        }

        if (tid == 0) sh_cnt = 0;
        __syncthreads();
        for (int i = tid; i < NBOX; i += NTH) {
            float s = sraw[(size_t)i * NCLSIN];
            unsigned k = (s > 0.3f) ? fmap(s) : 0u;
            if (k >= thr) {
                unsigned long long key =
                    ((unsigned long long)k << 32) | (0xFFFFFFFFu - (unsigned)i);
                if (key < lastk) {
                    int pos = atomicAdd(&sh_cnt, 1);
                    if (pos < CANDL) cand[pos] = key;
                }
            }
        }
        __syncthreads();
        const int M = sh_cnt < CANDL ? sh_cnt : CANDL;

        sort_desc(cand, M, tid);
        const int PBX = M < CBCAP ? M : CBCAP;
        for (int i = tid; i < PBX; i += NTH)
            candbox[i] = bbase[(int)(0xFFFFFFFFu - (unsigned)cand[i])];
        __syncthreads();
        walk_slow(cand, 0, M, bbase, candbox, sel0, sel1, sa0, sa1,
                  ss0, ss1, nsel, &sh_nsel, tid);
        if (nsel >= MAXSEL || E <= M) break;
        lastk = cand[M - 1];
        __syncthreads();
    }

    // ---- outputs: selections in greedy order, zero-padded ----
    if (tid < 64) {
        float* scp = ws_sc + (size_t)bc * MAXSEL;
        float4* bxp = (float4*)(ws_bx + (size_t)bc * MAXSEL * 4);
        {
            bool v = tid < nsel;
            scp[tid] = v ? ss0 : 0.f;
            bxp[tid] = v ? sel0 : make_float4(0.f, 0.f, 0.f, 0.f);
        }
        int j1 = tid + 64;
        if (j1 < MAXSEL) {
            bool v = j1 < nsel;
            scp[j1] = v ? ss1 : 0.f;
            bxp[j1] = v ? sel1 : make_float4(0.f, 0.f, 0.f, 0.f);
        }
    }
}

// ---------------------------------------------------------------------------
// Kernel 2: one block per batch: stable top-200 of 9000 via radix-select+sort.
// ---------------------------------------------------------------------------
__global__ __launch_bounds__(NTH) void topk_k(const float* __restrict__ ws_sc,
                                              const float* __restrict__ ws_bx,
                                              float* __restrict__ out_sc,
                                              float* __restrict__ out_bx) {
    __shared__ unsigned hist[BINS];
    __shared__ unsigned gbuf[NTH];
    __shared__ unsigned long long cand[CANDL];
    __shared__ unsigned sh_kmax, sh_pb;
    __shared__ int sh_E, sh_g, sh_b, sh_cnt;

    const int tid = threadIdx.x;
    const int b = blockIdx.x;
    const int NF = NCLS * MAXSEL;  // 9000
    const float* sp = ws_sc + (size_t)b * NF;

    unsigned km = 0, ce = 0;
    for (int f = tid; f < NF; f += NTH) {
        unsigned k = __float_as_uint(sp[f]);
        if (k) { ce++; km = km > k ? km : k; }
    }
#pragma unroll
    for (int off = 32; off > 0; off >>= 1) {
        unsigned o = (unsigned)__shfl_xor((int)km, off, 64);
        km = km > o ? km : o;
        ce += (unsigned)__shfl_xor((int)ce, off, 64);
    }
    if ((tid & 63) == 0) { gbuf[tid >> 6] = km; gbuf[8 + (tid >> 6)] = ce; }
    __syncthreads();
    if (tid == 0) {
        unsigned m2 = 0, c2 = 0;
        for (int w = 0; w < NTH / 64; ++w) {
            m2 = m2 > gbuf[w] ? m2 : gbuf[w];
            c2 += gbuf[8 + w];
        }
        sh_kmax = m2; sh_E = (int)c2;
    }
    __syncthreads();
    const int E = sh_E;
    const unsigned kmax = sh_kmax;

    unsigned thr = 1u;
    if (E > TOPK) {
        for (int shift = 8;; shift += 4) {
            for (int i = tid; i < BINS; i += NTH) hist[i] = 0u;
            __syncthreads();
            for (int f = tid; f < NF; f += NTH) {
                unsigned k = __float_as_uint(sp[f]);
                if (k) {
                    unsigned bin = (kmax - k) >> shift;
                    if (bin < BINS - 1) atomicAdd(&hist[bin], 1u);
                }
            }
            __syncthreads();
            bin_select(hist, gbuf, &sh_g, &sh_b, &sh_pb, tid, (unsigned)TOPK);
            if (sh_b < BINS - 1) {
                long long t = (long long)kmax - ((long long)(sh_b + 1) << shift) + 1;
                thr = (t < 1) ? 1u : (unsigned)t;
                break;
            }
        }
    }

    if (tid == 0) sh_cnt = 0;
    __syncthreads();
    for (int f = tid; f < NF; f += NTH) {
        unsigned k = __float_as_uint(sp[f]);
        if (k >= thr) {
            int pos = atomicAdd(&sh_cnt, 1);
            if (pos < CANDL)
                cand[pos] = ((unsigned long long)k << 32) | (0xFFFFFFFFu - (unsigned)f);
        }
    }
    __syncthreads();
    int M = sh_cnt < CANDL ? sh_cnt : CANDL;

    if (M < TOPK) {
        int lim = M + TOPK;
        if (lim > NF) lim = NF;
        for (int f = tid; f < lim; f += NTH) {
            unsigned k = __float_as_uint(sp[f]);
            if (k == 0) {
                int pos = atomicAdd(&sh_cnt, 1);
                if (pos < CANDL)
                    cand[pos] = (unsigned long long)(0xFFFFFFFFu - (unsigned)f);
            }
        }
        __syncthreads();
        M = sh_cnt < CANDL ? sh_cnt : CANDL;
    }

    sort_desc(cand, M, tid);

    for (int k = tid; k < TOPK; k += NTH) {
        float cls = 0.f, s = 0.f;
        float4 bx = make_float4(0.f, 0.f, 0.f, 0.f);
        if (k < M) {
            unsigned long long key = cand[k];
            unsigned f = 0xFFFFFFFFu - (unsigned)key;
            s = __uint_as_float((unsigned)(key >> 32));
            cls = (s > 0.f) ? (float)(f / MAXSEL + 1) : 0.f;
            bx = *(const float4*)(ws_bx + ((size_t)b * NF + f) * 4);
        }
        out_sc[((size_t)b * TOPK + k) * 2 + 0] = cls;
        out_sc[((size_t)b * TOPK + k) * 2 + 1] = s;
        ((float4*)out_bx)[(size_t)b * TOPK + k] = bx;
    }
}

// ---------------------------------------------------------------------------
extern "C" void kernel_launch(void* const* d_in, const int* in_sizes, int n_in,
                              void* d_out, int out_size, void* d_ws, size_t ws_size,
                              hipStream_t stream) {
    const float* scores = (const float*)d_in[0];
    const float4* boxes = (const float4*)d_in[1];
    float* out = (float*)d_out;

    const int B = in_sizes[1] / (NBOX * 4);
    const int NBC = B * NCLS;

    // ws layout: cnt [NBC * CNTSTR ints] | cand [NBC*CAP u64] | sc | bx
    size_t off_cand = ((size_t)NBC * CNTSTR * 4 + 15) & ~(size_t)15;
    size_t off_sc = off_cand + (size_t)NBC * CAP * 8;
    size_t off_bx = off_sc + (size_t)NBC * MAXSEL * 4;
    size_t need = off_bx + (size_t)NBC * MAXSEL * 16;

    char* ws = (char*)d_ws;
    bool use_band = ws_size >= need;

    int* cnt_g;
    unsigned long long* cand_g;
    float *ws_sc, *ws_bx;
    if (use_band) {
        cnt_g = (int*)ws;
        cand_g = (unsigned long long*)(ws + off_cand);
        ws_sc = (float*)(ws + off_sc);
        ws_bx = (float*)(ws + off_bx);
    } else {
        cnt_g = (int*)ws;                  // unused
        cand_g = (unsigned long long*)ws;  // unused
        ws_sc = (float*)ws;
        ws_bx = ws_sc + (size_t)NBC * MAXSEL;
    }

    if (use_band) {
        int n4 = NBC * CNTSTR / 4;
        zero_k<<<(n4 + NTH - 1) / NTH, NTH, 0, stream>>>((int4*)cnt_g, n4);
        filter_k<<<dim3(NBOX / BOXPB, B), NTH, 0, stream>>>(scores, cand_g, cnt_g);
    }
    nms_k<<<dim3(NCLS, B), NTH, 0, stream>>>(cand_g, cnt_g, scores, boxes,
                                             ws_sc, ws_bx, use_band ? 1 : 0);
    topk_k<<<B, NTH, 0, stream>>>(ws_sc, ws_bx, out, out + (size_t)B * TOPK * 2);
}

// Round 13
// 105.958 us; speedup vs baseline: 1.3087x; 1.0758x over previous
//
#include <hip/hip_runtime.h>

#define NTH 256
#define NBOX 16384
#define NCLSIN 91
#define NCLS 90
#define MAXSEL 100
#define TOPK 200
#define TSEL 256      // fallback radix-select size
#define CAP 1024      // candidate list stride per (b,c)
#define CANDL 512     // LDS band capacity (batch walk covers <=256)
#define CBCAP 256     // prefetched candidate boxes
#define BINS 1024
#define GRP 4         // BINS / NTH
#define T0 0.989f     // band threshold: E[C]=180, sigma 13.4; fallbacks guard
#define BOXPB 256     // boxes per filter block
#define KSL 16        // per-class LDS slots per filter block
#define OVFC 64       // LDS overflow list capacity
#define CNTSTR 16     // cnt_g stride in ints (64B per counter)

// order-preserving fp32 <-> u32 (strictly monotone for all non-NaN)
__device__ __forceinline__ unsigned fmap(float f) {
    unsigned u = __float_as_uint(f);
    return (u & 0x80000000u) ? ~u : (u | 0x80000000u);
}
__device__ __forceinline__ float funmap(unsigned u) {
    unsigned b = (u & 0x80000000u) ? (u ^ 0x80000000u) : ~u;
    return __uint_as_float(b);
}
__device__ __forceinline__ unsigned long long shfl_xor_u64(unsigned long long v, int mask) {
    unsigned lo = (unsigned)(v & 0xFFFFFFFFull);
    unsigned hi = (unsigned)(v >> 32);
    lo = __shfl_xor(lo, mask, 64);
    hi = __shfl_xor(hi, mask, 64);
    return ((unsigned long long)hi << 32) | (unsigned long long)lo;
}

// Exact reference IoU>0.5 with division-free fast path (r11, verified exact)
__device__ __forceinline__ bool sup_test(float4 s, float sa, float4 c, float ca) {
    float y1 = fmaxf(s.x, c.x);
    float x1 = fmaxf(s.y, c.y);
    float y2 = fminf(s.z, c.z);
    float x2 = fminf(s.w, c.w);
    float dy = fmaxf(__fsub_rn(y2, y1), 0.f);
    float dx = fmaxf(__fsub_rn(x2, x1), 0.f);
    float inter = __fmul_rn(dy, dx);
    float uni = __fsub_rn(__fadd_rn(sa, ca), inter);
    if (!(uni > 0.f)) return false;
    float t = 0.5f * uni;
    if (inter <= t) return false;
    if (inter > __fmul_rn(t, 1.0000005f)) return true;
    return __fdiv_rn(inter, uni) > 0.5f;
}
__device__ __forceinline__ float box_area(float4 b) {
    return __fmul_rn(__fsub_rn(b.z, b.x), __fsub_rn(b.w, b.y));
}

// ---------------------------------------------------------------------------
__global__ __launch_bounds__(NTH) void zero_k(int4* __restrict__ p, int n4) {
    int i = blockIdx.x * NTH + threadIdx.x;
    if (i < n4) p[i] = make_int4(0, 0, 0, 0);
}

__device__ __forceinline__ void bin_select(unsigned* hist, unsigned* gbuf,
                                           int* sh_g, int* sh_b, unsigned* sh_pb,
                                           int tid, unsigned need) {
    unsigned gs = 0;
#pragma unroll
    for (int q = 0; q < GRP; ++q) gs += hist[tid * GRP + q];
    gbuf[tid] = gs;
    __syncthreads();
    for (int off = 1; off < NTH; off <<= 1) {
        unsigned add = (tid >= off) ? gbuf[tid - off] : 0u;
        __syncthreads();
        gbuf[tid] += add;
        __syncthreads();
    }
    if (tid == 0) *sh_g = NTH - 1;
    __syncthreads();
    if (gbuf[tid] >= need && (tid == 0 || gbuf[tid - 1] < need)) *sh_g = tid;
    __syncthreads();
    if (tid == 0) {
        int g = *sh_g;
        unsigned acc = (g > 0) ? gbuf[g - 1] : 0u;
        int bs = g * GRP + (GRP - 1);
        unsigned pb = acc;
#pragma unroll
        for (int q = 0; q < GRP; ++q) {
            acc += hist[g * GRP + q];
            if (acc >= need) { bs = g * GRP + q; pb = acc; break; }
            pb = acc;
        }
        *sh_b = bs; *sh_pb = pb;
    }
    __syncthreads();
}

// LDS bitonic sort descending (fallback for 256 < C <= CANDL and refill)
__device__ __forceinline__ void sort_desc(unsigned long long* cand, int M, int tid) {
    int P = 1;
    while (P < M) P <<= 1;
    for (int i = M + tid; i < P; i += NTH) cand[i] = 0ull;
    __syncthreads();
    for (int kk = 2; kk <= P; kk <<= 1) {
        for (int jj = kk >> 1; jj > 0; jj >>= 1) {
            for (int i = tid; i < P; i += NTH) {
                int ixj = i ^ jj;
                if (ixj > i) {
                    unsigned long long a = cand[i], c = cand[ixj];
                    bool sw = ((i & kk) == 0) ? (a < c) : (a > c);
                    if (sw) { cand[i] = c; cand[ixj] = a; }
                }
            }
            __syncthreads();
        }
    }
}

// ---------------------------------------------------------------------------
// filter_k helper: route one hit into per-class LDS staging. Exact.
// ---------------------------------------------------------------------------
__device__ __forceinline__ void emit_hit(unsigned long long pk, int b, int n0,
                                         int* cnt_s, unsigned long long* ent,
                                         unsigned* ovf_meta,
                                         unsigned long long* ovf_key,
                                         int* sh_ovf, int* cnt_g) {
    unsigned ee = (unsigned)pk;
    int row = (int)ee / NCLSIN;
    int c = (int)ee - row * NCLSIN;
    if (c == 0) return;  // background
    unsigned i = (unsigned)(n0 + row);
    unsigned long long key = (pk & 0xFFFFFFFF00000000ull) | (0xFFFFFFFFu - i);
    int r = atomicAdd(&cnt_s[c], 1);
    if (r < KSL) {
        ent[c * KSL + r] = key;
    } else {
        int o = atomicAdd(sh_ovf, 1);
        if (o < OVFC) {
            ovf_meta[o] = ((unsigned)c << 16) | (unsigned)r;
            ovf_key[o] = key;
        } else {
            atomicAdd(&cnt_g[(b * NCLS + c - 1) * CNTSTR], CAP + 1);
        }
    }
}

// ---------------------------------------------------------------------------
// Kernel 0: stream scores once (2x float4/lane). Hits buffered in 4 per-lane
// registers, drained at end; >=5th hit spills to immediate path.
// ---------------------------------------------------------------------------
__global__ __launch_bounds__(NTH) void filter_k(const float* __restrict__ in,
                                                unsigned long long* __restrict__ cand_g,
                                                int* __restrict__ cnt_g) {
    __shared__ int cnt_s[NCLSIN];
    __shared__ int base_s[NCLSIN];
    __shared__ unsigned long long ent[NCLSIN * KSL];
    __shared__ unsigned ovf_meta[OVFC];
    __shared__ unsigned long long ovf_key[OVFC];
    __shared__ int sh_ovf;

    const int tid = threadIdx.x;
    const int n0 = blockIdx.x * BOXPB;
    const int b = blockIdx.y;
    const int NF4 = BOXPB * NCLSIN / 4;

    for (int i = tid; i < NCLSIN; i += NTH) cnt_s[i] = 0;
    if (tid == 0) sh_ovf = 0;
    __syncthreads();

    unsigned long long q0 = 0, q1 = 0, q2 = 0, q3 = 0;
    int lc = 0;

    const float4* src = (const float4*)(in + ((size_t)b * NBOX + n0) * NCLSIN);
    for (int i = tid; i < NF4; i += 2 * NTH) {
        float4 v1 = src[i];
        int i2 = i + NTH;
        bool has2 = i2 < NF4;
        float4 v2 = make_float4(0.f, 0.f, 0.f, 0.f);
        if (has2) v2 = src[i2];
        float mx1 = fmaxf(fmaxf(v1.x, v1.y), fmaxf(v1.z, v1.w));
        float mx2 = fmaxf(fmaxf(v2.x, v2.y), fmaxf(v2.z, v2.w));
        if (fmaxf(mx1, mx2) > T0) {
#pragma unroll
            for (int h = 0; h < 2; ++h) {
                float4 v = h ? v2 : v1;
                float mx = h ? mx2 : mx1;
                int eb = (h ? i2 : i) * 4;
                if (mx > T0) {
                    const float sv[4] = {v.x, v.y, v.z, v.w};
#pragma unroll
                    for (int qq = 0; qq < 4; ++qq) {
                        float s = sv[qq];
                        if (s > T0) {
                            unsigned long long pk =
                                ((unsigned long long)fmap(s) << 32) |
                                (unsigned)(eb + qq);
                            if (lc == 0) q0 = pk;
                            else if (lc == 1) q1 = pk;
                            else if (lc == 2) q2 = pk;
                            else if (lc == 3) q3 = pk;
                            else emit_hit(pk, b, n0, cnt_s, ent, ovf_meta,
                                          ovf_key, &sh_ovf, cnt_g);
                            ++lc;
                        }
                    }
                }
            }
        }
    }
    if (lc > 0) emit_hit(q0, b, n0, cnt_s, ent, ovf_meta, ovf_key, &sh_ovf, cnt_g);
    if (lc > 1) emit_hit(q1, b, n0, cnt_s, ent, ovf_meta, ovf_key, &sh_ovf, cnt_g);
    if (lc > 2) emit_hit(q2, b, n0, cnt_s, ent, ovf_meta, ovf_key, &sh_ovf, cnt_g);
    if (lc > 3) emit_hit(q3, b, n0, cnt_s, ent, ovf_meta, ovf_key, &sh_ovf, cnt_g);
    __syncthreads();

    if (tid >= 1 && tid < NCLSIN) {
        int c = tid;
        int n = cnt_s[c];
        int base = 0;
        if (n > 0) {
            int bc = b * NCLS + c - 1;
            base = atomicAdd(&cnt_g[bc * CNTSTR], n);
            int lim = n < KSL ? n : KSL;
            for (int j = 0; j < lim; ++j) {
                int pos = base + j;
                if (pos < CAP) cand_g[(size_t)bc * CAP + pos] = ent[c * KSL + j];
            }
        }
        base_s[c] = base;
    }
    __syncthreads();

    int no = sh_ovf < OVFC ? sh_ovf : OVFC;
    for (int o = tid; o < no; o += NTH) {
        unsigned m = ovf_meta[o];
        int c = (int)(m >> 16);
        int r = (int)(m & 0xFFFFu);
        int bc = b * NCLS + c - 1;
        int pos = base_s[c] + r;
        if (pos < CAP) cand_g[(size_t)bc * CAP + pos] = ovf_key[o];
    }
}

// ---------------------------------------------------------------------------
// Serial greedy walk vs LDS-resident selected list (exact; rare paths only).
// Wave 0: lane l tests selbox[l] and selbox[l+64].
// ---------------------------------------------------------------------------
__device__ __forceinline__ void serial_walk_lds(
    const unsigned long long* cand, int from, int to,
    const float4* __restrict__ bbase, const float4* candbox, const float* carea,
    float4* selbox, float* selarea, float* selscore,
    int& nsel, int* sh_nsel, int tid) {
    if (tid < 64) {
        for (int m = from; m < to && nsel < MAXSEL; ++m) {
            unsigned long long key = cand[m];
            float4 bx;
            float ca;
            if (m < CBCAP) { bx = candbox[m]; ca = carea[m]; }
            else { bx = bbase[(int)(0xFFFFFFFFu - (unsigned)key)]; ca = box_area(bx); }
            bool sup = false;
            if (tid < nsel) sup = sup_test(selbox[tid], selarea[tid], bx, ca);
            int l2 = tid + 64;
            if (l2 < nsel) sup = sup || sup_test(selbox[l2], selarea[l2], bx, ca);
            if (!__any(sup)) {
                if (tid == 0) {
                    selbox[nsel] = bx;
                    selarea[nsel] = ca;
                    selscore[nsel] = funmap((unsigned)(key >> 32));
                }
                nsel++;
            }
        }
        if (tid == 0) *sh_nsel = nsel;
    }
    __syncthreads();
    nsel = *sh_nsel;
    __syncthreads();
}

// ---------------------------------------------------------------------------
// Kernel 1: one block per (batch, class).
// C<=256: reg bitonic sort -> precomputed intra-batch suppression matrices ->
// 64-wide tentative-select batch walk (exact: ordered sparse resolution).
// 256<C<=CANDL: LDS sort + serial walk. Refill fallback below band. Exact.
// ---------------------------------------------------------------------------
__global__ __launch_bounds__(NTH) void nms_k(
    const unsigned long long* __restrict__ cand_g,
    const int* __restrict__ cnt_g,
    const float* __restrict__ scores_raw,
    const float4* __restrict__ boxes,
    float* __restrict__ ws_sc, float* __restrict__ ws_bx, int use_band) {
    __shared__ unsigned long long cand[CANDL];  // 4 KB
    __shared__ float4 candbox[CBCAP];           // 4 KB (aliased as hist in fallback)
    __shared__ float carea[CBCAP];              // 1 KB
    __shared__ float4 selbox[MAXSEL];           // 1.6 KB
    __shared__ float selarea[MAXSEL];
    __shared__ float selscore[MAXSEL];
    __shared__ unsigned M32[CBCAP * 2];         // 2 KB: per-cand 64-bit intra-batch mask
    __shared__ unsigned gbuf[NTH];              // 1 KB
    __shared__ unsigned sh_kmax, sh_pb;
    __shared__ int sh_E, sh_g, sh_b, sh_cnt, sh_nsel;
    unsigned* hist = (unsigned*)candbox;  // candbox dead while hist live

    const int tid = threadIdx.x;
    const int c0 = blockIdx.x;
    const int b = blockIdx.y;
    const int bc = b * NCLS + c0;
    const float* sraw = scores_raw + (size_t)b * NBOX * NCLSIN + (c0 + 1);
    const float4* bbase = boxes + (size_t)b * NBOX;

    int nsel = 0;
    unsigned long long lastk = ~0ull;

    if (use_band) {
        const int C = cnt_g[bc * CNTSTR];
        if (C > 0 && C <= CANDL) {
            if (C <= 256) {
                // ---- register bitonic sort descending (r12, verified) ----
                unsigned long long v =
                    (tid < C) ? cand_g[(size_t)bc * CAP + tid] : 0ull;
#pragma unroll
                for (int kk = 2; kk <= 256; kk <<= 1) {
#pragma unroll
                    for (int jj = kk >> 1; jj > 0; jj >>= 1) {
                        unsigned long long o;
                        if (jj >= 64) {
                            cand[tid] = v;
                            __syncthreads();
                            o = cand[tid ^ jj];
                            __syncthreads();
                        } else {
                            o = shfl_xor_u64(v, jj);
                        }
                        bool lower = (tid & jj) == 0;
                        bool desc = (tid & kk) == 0;
                        v = (lower == desc) ? (v > o ? v : o) : (v < o ? v : o);
                    }
                }
                cand[tid] = v;
                __syncthreads();

                // ---- gather boxes + zero M ----
                if (tid < C) {
                    float4 bx = bbase[(int)(0xFFFFFFFFu - (unsigned)cand[tid])];
                    candbox[tid] = bx;
                    carea[tid] = box_area(bx);
                }
                M32[tid] = 0;
                M32[tid + NTH] = 0;
                __syncthreads();

                // ---- intra-batch matrices: all batches, all 256 threads.
                // pair q in [0,2016) -> (i,j), j<i<64; bit j of M[bt*64+i].
                const int nbatch = (C + 63) >> 6;
                for (int p = tid; p < nbatch * 2016; p += NTH) {
                    int bt = p / 2016;
                    int q = p - bt * 2016;
                    int i = (int)((1.0f + sqrtf(1.0f + 8.0f * (float)q)) * 0.5f);
                    while (i * (i - 1) / 2 > q) --i;
                    while ((i + 1) * i / 2 <= q) ++i;
                    int j = q - i * (i - 1) / 2;
                    int gm = bt * 64 + i, gj = bt * 64 + j;
                    if (gm < C) {
                        if (sup_test(candbox[gj], carea[gj], candbox[gm], carea[gm]))
                            atomicOr(&M32[gm * 2 + (j >> 5)], 1u << (j & 31));
                    }
                }
                __syncthreads();

                // ---- batch walk (wave 0): tentative-select + ordered
                // resolution of the sparse intra-batch dependency set.
                if (tid < 64) {
                    for (int bt = 0; bt < nbatch && nsel < MAXSEL; ++bt) {
                        int m = bt * 64 + tid;
                        bool active = m < C;
                        float4 bx = make_float4(0.f, 0.f, 0.f, 0.f);
                        float ca = 0.f;
                        unsigned long long key = 0ull;
                        unsigned long long myM = 0ull;
                        if (active) {
                            key = cand[m];
                            bx = candbox[m];
                            ca = carea[m];
                            myM = ((unsigned long long)M32[m * 2 + 1] << 32) |
                                  M32[m * 2];
                        }
                        // vs previously-selected (broadcast LDS reads)
                        bool supV = !active;
                        for (int j = 0; j < nsel; ++j) {
                            if (active)
                                supV = supV || sup_test(selbox[j], selarea[j], bx, ca);
                        }
                        unsigned long long selb = ~__ballot(supV);  // tentative
                        // ordered resolution of candidates with intra-batch deps
                        unsigned long long U = __ballot(myM != 0ull) & selb;
                        while (U) {
                            int mm = __builtin_ctzll(U);
                            U &= U - 1ull;
                            unsigned long long Mm =
                                ((unsigned long long)M32[(bt * 64 + mm) * 2 + 1] << 32) |
                                M32[(bt * 64 + mm) * 2];
                            unsigned long long below =
                                (mm == 0) ? 0ull : ((1ull << mm) - 1ull);
                            if ((selb >> mm) & 1ull) {
                                if (Mm & selb & below) selb &= ~(1ull << mm);
                            }
                        }
                        // cap at MAXSEL: keep lowest-index bits (= greedy stop)
                        int avail = MAXSEL - nsel;
                        int pop = __builtin_popcountll(selb);
                        while (pop > avail) {
                            selb &= ~(1ull << (63 - __builtin_clzll(selb)));
                            --pop;
                        }
                        // rank-write selections
                        if ((selb >> tid) & 1ull) {
                            unsigned long long below =
                                (tid == 0) ? 0ull : ((1ull << tid) - 1ull);
                            int pos = nsel + __builtin_popcountll(selb & below);
                            selbox[pos] = bx;
                            selarea[pos] = ca;
                            selscore[pos] = funmap((unsigned)(key >> 32));
                        }
                        nsel += pop;
                    }
                    if (tid == 0) sh_nsel = nsel;
                }
                __syncthreads();
                nsel = sh_nsel;
                __syncthreads();
            } else {
                // rare (>5 sigma): LDS sort + serial walk
                for (int i = tid; i < C; i += NTH)
                    cand[i] = cand_g[(size_t)bc * CAP + i];
                sort_desc(cand, C, tid);
                const int PBX = C < CBCAP ? C : CBCAP;
                for (int i = tid; i < PBX; i += NTH) {
                    float4 bx = bbase[(int)(0xFFFFFFFFu - (unsigned)cand[i])];
                    candbox[i] = bx;
                    carea[i] = box_area(bx);
                }
                __syncthreads();
                serial_walk_lds(cand, 0, C, bbase, candbox, carea,
                                selbox, selarea, selscore, nsel, &sh_nsel, tid);
            }
            lastk = cand[C - 1];
        }
        // C==0 or C>CANDL: lastk stays ~0 -> exact full fallback below
    }

    while (nsel < MAXSEL) {
        // ---- eligible count + max key (keys strictly below lastk) ----
        unsigned km = 0, ce = 0;
        for (int i = tid; i < NBOX; i += NTH) {
            float s = sraw[(size_t)i * NCLSIN];
            unsigned k = (s > 0.3f) ? fmap(s) : 0u;
            if (k) {
                unsigned long long key =
                    ((unsigned long long)k << 32) | (0xFFFFFFFFu - (unsigned)i);
                if (key < lastk) { ce++; km = km > k ? km : k; }
            }
        }
#pragma unroll
        for (int off = 32; off > 0; off >>= 1) {
            unsigned o = (unsigned)__shfl_xor((int)km, off, 64);
            km = km > o ? km : o;
            ce += (unsigned)__shfl_xor((int)ce, off, 64);
        }
        if ((tid & 63) == 0) { gbuf[tid >> 6] = km; gbuf[8 + (tid >> 6)] = ce; }
        __syncthreads();
        if (tid == 0) {
            unsigned m2 = 0, c2 = 0;
            for (int w = 0; w < NTH / 64; ++w) {
                m2 = m2 > gbuf[w] ? m2 : gbuf[w];
                c2 += gbuf[8 + w];
            }
            sh_kmax = m2; sh_E = (int)c2;
        }
        __syncthreads();
        const int E = sh_E;
        const unsigned kmax = sh_kmax;
        if (E == 0) break;

        unsigned thr = 1u;
        if (E > TSEL) {
            for (int shift = 8;; shift += 4) {
                for (int i = tid; i < BINS; i += NTH) hist[i] = 0u;
                __syncthreads();
                for (int i = tid; i < NBOX; i += NTH) {
                    float s = sraw[(size_t)i * NCLSIN];
                    unsigned k = (s > 0.3f) ? fmap(s) : 0u;
                    if (k) {
                        unsigned long long key =
                            ((unsigned long long)k << 32) | (0xFFFFFFFFu - (unsigned)i);
                        if (key < lastk) {
                            unsigned bin = (kmax - k) >> shift;
                            if (bin < BINS - 1) atomicAdd(&hist[bin], 1u);
                        }
                    }
                }
                __syncthreads();
                bin_select(hist, gbuf, &sh_g, &sh_b, &sh_pb, tid, (unsigned)TSEL);
                if (sh_b < BINS - 1) {
                    long long t = (long long)kmax - ((long long)(sh_b + 1) << shift) + 1;
                    thr = (t < 1) ? 1u : (unsigned)t;
                    break;
                }
            }
        }

        if (tid == 0) sh_cnt = 0;
        __syncthreads();
        for (int i = tid; i < NBOX; i += NTH) {
            float s = sraw[(size_t)i * NCLSIN];
            unsigned k = (s > 0.3f) ? fmap(s) : 0u;
            if (k >= thr) {
                unsigned long long key =
                    ((unsigned long long)k << 32) | (0xFFFFFFFFu - (unsigned)i);
                if (key < lastk) {
                    int pos = atomicAdd(&sh_cnt, 1);
                    if (pos < CANDL) cand[pos] = key;
                }
            }
        }
        __syncthreads();
        const int M = sh_cnt < CANDL ? sh_cnt : CANDL;

        sort_desc(cand, M, tid);
        const int PBX = M < CBCAP ? M : CBCAP;
        for (int i = tid; i < PBX; i += NTH) {
            float4 bx = bbase[(int)(0xFFFFFFFFu - (unsigned)cand[i])];
            candbox[i] = bx;
            carea[i] = box_area(bx);
        }
        __syncthreads();
        serial_walk_lds(cand, 0, M, bbase, candbox, carea,
                        selbox, selarea, selscore, nsel, &sh_nsel, tid);
        if (nsel >= MAXSEL || E <= M) break;
        lastk = cand[M - 1];
        __syncthreads();
    }

    // ---- outputs: selections in greedy order, zero-padded ----
    if (tid < MAXSEL) {
        bool v = tid < nsel;
        ws_sc[(size_t)bc * MAXSEL + tid] = v ? selscore[tid] : 0.f;
        ((float4*)ws_bx)[(size_t)bc * MAXSEL + tid] =
            v ? selbox[tid] : make_float4(0.f, 0.f, 0.f, 0.f);
    }
}

// ---------------------------------------------------------------------------
// Kernel 2: one block per batch: stable top-200 of 9000 via radix-select+sort.
// ---------------------------------------------------------------------------
__global__ __launch_bounds__(NTH) void topk_k(const float* __restrict__ ws_sc,
                                              const float* __restrict__ ws_bx,
                                              float* __restrict__ out_sc,
                                              float* __restrict__ out_bx) {
    __shared__ unsigned hist[BINS];
    __shared__ unsigned gbuf[NTH];
    __shared__ unsigned long long cand[CANDL];
    __shared__ unsigned sh_kmax, sh_pb;
    __shared__ int sh_E, sh_g, sh_b, sh_cnt;

    const int tid = threadIdx.x;
    const int b = blockIdx.x;
    const int NF = NCLS * MAXSEL;  // 9000
    const float* sp = ws_sc + (size_t)b * NF;

    unsigned km = 0, ce = 0;
    for (int f = tid; f < NF; f += NTH) {
        unsigned k = __float_as_uint(sp[f]);
        if (k) { ce++; km = km > k ? km : k; }
    }
#pragma unroll
    for (int off = 32; off > 0; off >>= 1) {
        unsigned o = (unsigned)__shfl_xor((int)km, off, 64);
        km = km > o ? km : o;
        ce += (unsigned)__shfl_xor((int)ce, off, 64);
    }
    if ((tid & 63) == 0) { gbuf[tid >> 6] = km; gbuf[8 + (tid >> 6)] = ce; }
    __syncthreads();
    if (tid == 0) {
        unsigned m2 = 0, c2 = 0;
        for (int w = 0; w < NTH / 64; ++w) {
            m2 = m2 > gbuf[w] ? m2 : gbuf[w];
            c2 += gbuf[8 + w];
        }
        sh_kmax = m2; sh_E = (int)c2;
    }
    __syncthreads();
    const int E = sh_E;
    const unsigned kmax = sh_kmax;

    unsigned thr = 1u;
    if (E > TOPK) {
        for (int shift = 8;; shift += 4) {
            for (int i = tid; i < BINS; i += NTH) hist[i] = 0u;
            __syncthreads();
            for (int f = tid; f < NF; f += NTH) {
                unsigned k = __float_as_uint(sp[f]);
                if (k) {
                    unsigned bin = (kmax - k) >> shift;
                    if (bin < BINS - 1) atomicAdd(&hist[bin], 1u);
                }
            }
            __syncthreads();
            bin_select(hist, gbuf, &sh_g, &sh_b, &sh_pb, tid, (unsigned)TOPK);
            if (sh_b < BINS - 1) {
                long long t = (long long)kmax - ((long long)(sh_b + 1) << shift) + 1;
                thr = (t < 1) ? 1u : (unsigned)t;
                break;
            }
        }
    }

    if (tid == 0) sh_cnt = 0;
    __syncthreads();
    for (int f = tid; f < NF; f += NTH) {
        unsigned k = __float_as_uint(sp[f]);
        if (k >= thr) {
            int pos = atomicAdd(&sh_cnt, 1);
            if (pos < CANDL)
                cand[pos] = ((unsigned long long)k << 32) | (0xFFFFFFFFu - (unsigned)f);
        }
    }
    __syncthreads();
    int M = sh_cnt < CANDL ? sh_cnt : CANDL;

    if (M < TOPK) {
        int lim = M + TOPK;
        if (lim > NF) lim = NF;
        for (int f = tid; f < lim; f += NTH) {
            unsigned k = __float_as_uint(sp[f]);
            if (k == 0) {
                int pos = atomicAdd(&sh_cnt, 1);
                if (pos < CANDL)
                    cand[pos] = (unsigned long long)(0xFFFFFFFFu - (unsigned)f);
            }
        }
        __syncthreads();
        M = sh_cnt < CANDL ? sh_cnt : CANDL;
    }

    sort_desc(cand, M, tid);

    for (int k = tid; k < TOPK; k += NTH) {
        float cls = 0.f, s = 0.f;
        float4 bx = make_float4(0.f, 0.f, 0.f, 0.f);
        if (k < M) {
            unsigned long long key = cand[k];
            unsigned f = 0xFFFFFFFFu - (unsigned)key;
            s = __uint_as_float((unsigned)(key >> 32));
            cls = (s > 0.f) ? (float)(f / MAXSEL + 1) : 0.f;
            bx = *(const float4*)(ws_bx + ((size_t)b * NF + f) * 4);
        }
        out_sc[((size_t)b * TOPK + k) * 2 + 0] = cls;
        out_sc[((size_t)b * TOPK + k) * 2 + 1] = s;
        ((float4*)out_bx)[(size_t)b * TOPK + k] = bx;
    }
}

// ---------------------------------------------------------------------------
extern "C" void kernel_launch(void* const* d_in, const int* in_sizes, int n_in,
                              void* d_out, int out_size, void* d_ws, size_t ws_size,
                              hipStream_t stream) {
    const float* scores = (const float*)d_in[0];
    const float4* boxes = (const float4*)d_in[1];
    float* out = (float*)d_out;

    const int B = in_sizes[1] / (NBOX * 4);
    const int NBC = B * NCLS;

    // ws layout: cnt [NBC * CNTSTR ints] | cand [NBC*CAP u64] | sc | bx
    size_t off_cand = ((size_t)NBC * CNTSTR * 4 + 15) & ~(size_t)15;
    size_t off_sc = off_cand + (size_t)NBC * CAP * 8;
    size_t off_bx = off_sc + (size_t)NBC * MAXSEL * 4;
    size_t need = off_bx + (size_t)NBC * MAXSEL * 16;

    char* ws = (char*)d_ws;
    bool use_band = ws_size >= need;

    int* cnt_g;
    unsigned long long* cand_g;
    float *ws_sc, *ws_bx;
    if (use_band) {
        cnt_g = (int*)ws;
        cand_g = (unsigned long long*)(ws + off_cand);
        ws_sc = (float*)(ws + off_sc);
        ws_bx = (float*)(ws + off_bx);
    } else {
        cnt_g = (int*)ws;                  // unused
        cand_g = (unsigned long long*)ws;  // unused
        ws_sc = (float*)ws;
        ws_bx = ws_sc + (size_t)NBC * MAXSEL;
    }

    if (use_band) {
        int n4 = NBC * CNTSTR / 4;
        zero_k<<<(n4 + NTH - 1) / NTH, NTH, 0, stream>>>((int4*)cnt_g, n4);
        filter_k<<<dim3(NBOX / BOXPB, B), NTH, 0, stream>>>(scores, cand_g, cnt_g);
    }
    nms_k<<<dim3(NCLS, B), NTH, 0, stream>>>(cand_g, cnt_g, scores, boxes,
                                             ws_sc, ws_bx, use_band ? 1 : 0);
    topk_k<<<B, NTH, 0, stream>>>(ws_sc, ws_bx, out, out + (size_t)B * TOPK * 2);
}